// Round 12
// baseline (231.854 us; speedup 1.0000x reference)
//
#include <hip/hip_runtime.h>
#include <stdint.h>
#include <stddef.h>

#define Bb 128
#define Nn 512
#define Hh 128
#define ROWS (Bb*Nn)

typedef __bf16 bf16;
typedef __bf16 bf16x2 __attribute__((ext_vector_type(2)));
typedef __bf16 bf16x4 __attribute__((ext_vector_type(4)));
typedef __bf16 bf16x8 __attribute__((ext_vector_type(8)));
typedef float  f32x4  __attribute__((ext_vector_type(4)));

__device__ __forceinline__ void glds16(const void* g, void* l) {
  __builtin_amdgcn_global_load_lds(
      (const __attribute__((address_space(1))) void*)g,
      (__attribute__((address_space(3))) void*)l, 16, 0, 0);
}

// -------------------------------------------------- weight prep (all in one)
// fp32 W[k][c] -> bf16 W^T[c][k ^ ((c&7)<<3)]  (swizzle pre-applied)
__global__ __launch_bounds__(256) void prep_all(
    const float* __restrict__ eW1, const float* __restrict__ Wm,
    const float* __restrict__ Wu, bf16* __restrict__ WTe,
    bf16* __restrict__ WTm, bf16* __restrict__ WTu) {
  int idx = blockIdx.x*256 + threadIdx.x;
  if (idx < 16384) {                       // eW1: 128x128
    int k = idx >> 7, c = idx & 127;
    WTe[c*128 + (k ^ ((c & 7) << 3))] = (bf16)eW1[idx];
  } else if (idx < 16384 + 49152) {        // Wm: 3x128x128
    int sub = idx - 16384;
    int m = sub >> 14, r = sub & 16383;
    int k = r >> 7, c = r & 127;
    WTm[m*16384 + c*128 + (k ^ ((c & 7) << 3))] = (bf16)Wm[sub];
  } else if (idx < 16384 + 49152 + 98304) { // Wu: 3x256x128
    int sub = idx - 65536;
    int m = sub >> 15, r = sub & 32767;
    int k = r >> 7, c = r & 127;
    WTu[m*32768 + c*256 + (k ^ ((c & 7) << 3))] = (bf16)Wu[sub];
  }
}

// -------------------------------------------------- P materialization (once)
// E_ij = exp(2 x_i.x_j - |x_j|^2 - pen_j - |x_i|^2) in (0,1], stored bf16
// UNNORMALIZED in fragment-friendly row-major P[b][i][j]; rsum = 1/sum_j E.
// Same FP ops/order as the old in-loop computeA -> bit-identical results.
__global__ __launch_bounds__(256) void pmat_kernel(
    const float* __restrict__ jets, const float* __restrict__ mask,
    bf16* __restrict__ P, float* __restrict__ rsum) {
  __shared__ float Xs[Nn*9];
  __shared__ float cbs[Nn];
  const int t = threadIdx.x;
  const int b = blockIdx.x & 127, ic = blockIdx.x >> 7;
  const int i0 = ic*128;
  const float* jb = jets + (size_t)b*Nn*8;
  for (int j = t; j < Nn; j += 256) {
    float s2 = 0.f;
#pragma unroll
    for (int f = 0; f < 8; ++f) { float v = jb[j*8+f]; Xs[j*9+f] = v; s2 = fmaf(v,v,s2); }
    cbs[j] = s2 + (mask[(size_t)b*Nn+j] > 0.f ? 0.f : 1e9f);
  }
  __syncthreads();
  const int w = t >> 6, lane = t & 63, l15 = lane & 15, g = lane >> 4;
  const int i0w = i0 + w*32;
  float xi2[2][8], sqi[2], lsum[2];
#pragma unroll
  for (int r = 0; r < 2; ++r) {
    int i = i0w + r*16 + l15;
    float sq = 0.f;
#pragma unroll
    for (int f = 0; f < 8; ++f) {
      float v = Xs[i*9+f];
      xi2[r][f] = 2.f*v;
      sq = fmaf(v, v, sq);
    }
    sqi[r] = sq;
    lsum[r] = 0.f;
  }
  bf16* Pr[2];
#pragma unroll
  for (int r = 0; r < 2; ++r)
    Pr[r] = P + ((size_t)(b*512) + i0w + r*16 + l15)*512 + 8*g;
#pragma unroll 2
  for (int j0 = 0; j0 < Nn; j0 += 32) {
    bf16x8 pfr[2];
#pragma unroll
    for (int e = 0; e < 8; ++e) {
      int j = j0 + 8*g + e;
      float xj[8];
#pragma unroll
      for (int f = 0; f < 8; ++f) xj[f] = Xs[j*9+f];
      float cb = cbs[j];
      float d0 = -(cb + sqi[0]);
      float d1 = -(cb + sqi[1]);
#pragma unroll
      for (int f = 0; f < 8; ++f) {
        d0 = fmaf(xi2[0][f], xj[f], d0);
        d1 = fmaf(xi2[1][f], xj[f], d1);
      }
      float ev0 = __expf(d0), ev1 = __expf(d1);
      lsum[0] += ev0; lsum[1] += ev1;
      pfr[0][e] = (bf16)ev0;
      pfr[1][e] = (bf16)ev1;
    }
#pragma unroll
    for (int r = 0; r < 2; ++r)
      *(bf16x8*)(Pr[r] + j0) = pfr[r];
  }
#pragma unroll
  for (int r = 0; r < 2; ++r) {
    float s = lsum[r];
    s += __shfl_xor(s, 16, 64);
    s += __shfl_xor(s, 32, 64);
    if (g == 0) rsum[(size_t)b*Nn + i0w + r*16 + l15] = 1.f/s;
  }
}

// -------------------------------------------------- fused embed L1+L2+msg0
// h = relu(relu(jets@W0+b0)@W1+b1); msgT0 = relu(h@Wm0+bm0)^T. 128 rows/block.
__global__ __launch_bounds__(256) void embed_msg0(
    const float* __restrict__ jets, const float* __restrict__ W0,
    const float* __restrict__ b0, const bf16* __restrict__ WTe,
    const float* __restrict__ b1, const bf16* __restrict__ WTm0,
    const float* __restrict__ bm0, bf16* __restrict__ h,
    bf16* __restrict__ msgT) {
  __shared__ float sW0[8*128];
  __shared__ float sb0[128];
  __shared__ bf16 h0s[128*128];   // swizzled; reused for h-tile later
  __shared__ bf16 sWT[128*128];   // swizzled W1^T
  const int t = threadIdx.x;
  const int w = t >> 6, lane = t & 63, l15 = lane & 15, g = lane >> 4;
  const int row_blk = blockIdx.x*128;
  for (int q = w; q < 32; q += 4)
    glds16((const char*)WTe + q*1024 + lane*16, (char*)(void*)sWT + q*1024);
  for (int i = t; i < 8*128; i += 256) sW0[i] = W0[i];
  if (t < 128) sb0[t] = b0[t];
  __syncthreads();
  // layer 1: thread owns 1 row, 64 cols
  {
    const int row = t & 127, colbase = (t >> 7) * 64;
    const float4* jp = (const float4*)(jets + ((size_t)row_blk + row)*8);
    float4 x0 = jp[0], x1 = jp[1];
    float x[8] = {x0.x,x0.y,x0.z,x0.w,x1.x,x1.y,x1.z,x1.w};
    const int sw = (row & 7) << 3;
#pragma unroll
    for (int cg = 0; cg < 16; ++cg) {
      int c0 = colbase + cg*4;
      bf16x4 o;
#pragma unroll
      for (int j = 0; j < 4; ++j) {
        float a = sb0[c0+j];
#pragma unroll
        for (int f = 0; f < 8; ++f) a = fmaf(x[f], sW0[f*128 + c0 + j], a);
        o[j] = (bf16)fmaxf(a, 0.f);
      }
      *(bf16x4*)(h0s + row*128 + (c0 ^ sw)) = o;
    }
  }
  __syncthreads();
  // layer 2: MFMA, 4 waves 2x2
  const int wr = (w & 1)*64, wc = (w >> 1)*64;
  f32x4 acc[4][4];
#pragma unroll
  for (int m = 0; m < 4; ++m)
#pragma unroll
    for (int n = 0; n < 4; ++n) acc[m][n] = (f32x4){0.f,0.f,0.f,0.f};
#pragma unroll
  for (int kk = 0; kk < 128; kk += 32) {
    bf16x8 bfr[4], wfr[4];
#pragma unroll
    for (int n = 0; n < 4; ++n) {
      int row = wr + n*16 + l15;
      bfr[n] = *(const bf16x8*)(h0s + row*128 + ((kk + 8*g) ^ ((row & 7) << 3)));
    }
#pragma unroll
    for (int m = 0; m < 4; ++m) {
      int c = wc + m*16 + l15;
      wfr[m] = *(const bf16x8*)(sWT + c*128 + ((kk + 8*g) ^ ((c & 7) << 3)));
    }
#pragma unroll
    for (int m = 0; m < 4; ++m)
#pragma unroll
      for (int n = 0; n < 4; ++n)
        acc[m][n] = __builtin_amdgcn_mfma_f32_16x16x32_bf16(wfr[m], bfr[n], acc[m][n], 0,0,0);
  }
  __syncthreads();   // everyone done reading h0s before overwrite
#pragma unroll
  for (int m = 0; m < 4; ++m) {
    f32x4 bs = *(const f32x4*)(b1 + wc + m*16 + g*4);
#pragma unroll
    for (int n = 0; n < 4; ++n) {
      int lr = wr + n*16 + l15;
      int r = row_blk + lr;
      int c0 = wc + m*16 + g*4;
      bf16x4 o;
#pragma unroll
      for (int j = 0; j < 4; ++j) o[j] = (bf16)fmaxf(acc[m][n][j] + bs[j], 0.f);
      *(bf16x4*)(h + (size_t)r*128 + c0) = o;
      *(bf16x4*)(h0s + lr*128 + (c0 ^ ((lr & 7) << 3))) = o;
    }
  }
  __syncthreads();
  // msg0: msgT = relu(htile @ Wm0 + bm0), TRANSOUT; Wm0 frags from global(L2)
  {
    f32x4 acc2[4][4];
#pragma unroll
    for (int m = 0; m < 4; ++m)
#pragma unroll
      for (int n = 0; n < 4; ++n) acc2[m][n] = (f32x4){0.f,0.f,0.f,0.f};
#pragma unroll
    for (int kk = 0; kk < 128; kk += 32) {
      bf16x8 bfr[4], wfr[4];
#pragma unroll
      for (int n = 0; n < 4; ++n) {
        int lr = wr + n*16 + l15;
        bfr[n] = *(const bf16x8*)(h0s + lr*128 + ((kk + 8*g) ^ ((lr & 7) << 3)));
      }
#pragma unroll
      for (int m = 0; m < 4; ++m) {
        int c = wc + m*16 + l15;
        wfr[m] = *(const bf16x8*)(WTm0 + c*128 + ((kk + 8*g) ^ ((c & 7) << 3)));
      }
#pragma unroll
      for (int m = 0; m < 4; ++m)
#pragma unroll
        for (int n = 0; n < 4; ++n)
          acc2[m][n] = __builtin_amdgcn_mfma_f32_16x16x32_bf16(bfr[n], wfr[m], acc2[m][n], 0,0,0);
    }
    const int b = row_blk >> 9;
    const int rbase = (row_blk & 511) + wr;
#pragma unroll
    for (int m = 0; m < 4; ++m) {
      int c = wc + m*16 + l15;
      float bc = bm0[c];
#pragma unroll
      for (int n = 0; n < 4; ++n) {
        int rl = rbase + n*16 + g*4;
        bf16x4 o;
#pragma unroll
        for (int j = 0; j < 4; ++j) o[j] = (bf16)fmaxf(acc2[m][n][j] + bc, 0.f);
        *(bf16x4*)(msgT + ((size_t)(b*128 + c))*512 + rl) = o;
      }
    }
  }
}

// -------------------------------------------------- fused per-iteration kernel
// Phase A is now a pure GEMM: agg^T-frag = sum_j msgT-frag x P-frag, with P
// read from the materialized bf16 E matrix (L3-resident) and normalized by
// rsum in the epilogue (bit-identical to the old in-loop recompute).
// Phase B: h_new = relu([h|agg]@Wu+bu)*mask (in-place h).
// Phase C (DO_MSG): msgTout = relu(h_new@Wm+bm)^T. msgTin != msgTout.
// Block = (batch b = wgid&127 [XCD-pinned], 128-row chunk ic = wgid>>7).
template<bool DO_MSG>
__global__ __launch_bounds__(256) void iter_fused(
    const bf16* __restrict__ P, const float* __restrict__ rsum,
    const float* __restrict__ mask, const bf16* __restrict__ msgTin,
    bf16* __restrict__ h,
    const bf16* __restrict__ WTu, const float* __restrict__ bu,
    const bf16* __restrict__ WTm, const float* __restrict__ bm,
    bf16* __restrict__ msgTout) {
  __shared__ __align__(16) char smem[65536];
  bf16* htile = (bf16*)smem;                 // [128][128] 32KB
  bf16* aggs  = (bf16*)(smem + 32768);       // [128][128] 32KB
  const int t = threadIdx.x;
  const int b  = blockIdx.x & 127;
  const int ic = blockIdx.x >> 7;             // 0..3
  const int i0 = ic*128;
  const int w = t >> 6, lane = t & 63, l15 = lane & 15, g = lane >> 4;

  // ================= Phase A: agg rows i0 + w*32 .. +31 (pure GEMM)
  {
    const int i0w = i0 + w*32;
    float r_i[2];
#pragma unroll
    for (int r = 0; r < 2; ++r) r_i[r] = rsum[(size_t)b*Nn + i0w + r*16 + l15];
    f32x4 acc[2][8];
#pragma unroll
    for (int r = 0; r < 2; ++r)
#pragma unroll
      for (int m = 0; m < 8; ++m) acc[r][m] = (f32x4){0.f,0.f,0.f,0.f};
    const bf16* mB = msgTin + (size_t)b*128*512 + (size_t)l15*512 + 8*g;
    const bf16* pB[2];
#pragma unroll
    for (int r = 0; r < 2; ++r)
      pB[r] = P + ((size_t)(b*512) + i0w + r*16 + l15)*512 + 8*g;
#pragma unroll 4
    for (int j0 = 0; j0 < Nn; j0 += 32) {
      bf16x8 afr[8];
#pragma unroll
      for (int m = 0; m < 8; ++m)
        afr[m] = *(const bf16x8*)(mB + m*8192 + j0);
      bf16x8 pfr[2];
#pragma unroll
      for (int r = 0; r < 2; ++r)
        pfr[r] = *(const bf16x8*)(pB[r] + j0);
#pragma unroll
      for (int m = 0; m < 8; ++m)
#pragma unroll
        for (int r = 0; r < 2; ++r)
          acc[r][m] = __builtin_amdgcn_mfma_f32_16x16x32_bf16(afr[m], pfr[r], acc[r][m], 0,0,0);
    }
    // epilogue -> aggs LDS (swizzled), normalized by r_i
#pragma unroll
    for (int r = 0; r < 2; ++r) {
      int lr = w*32 + r*16 + l15;      // local row 0..127
#pragma unroll
      for (int m = 0; m < 8; ++m) {
        bf16x4 o;
#pragma unroll
        for (int j = 0; j < 4; ++j) o[j] = (bf16)(acc[r][m][j] * r_i[r]);
        int c0 = m*16 + g*4;
        *(bf16x4*)(aggs + lr*128 + (c0 ^ ((lr & 7) << 3))) = o;
      }
    }
  }
  __syncthreads();   // aggs visible to all waves

  // ================= Phase B: h_new = relu([h|agg] @ Wu + bu) * mask
  const int wr = (w & 1)*64, wc = (w >> 1)*64;
  const size_t growbase = (size_t)b*Nn + i0;
  {
    f32x4 acc[4][4];
#pragma unroll
    for (int m = 0; m < 4; ++m)
#pragma unroll
      for (int n = 0; n < 4; ++n) acc[m][n] = (f32x4){0.f,0.f,0.f,0.f};
#pragma unroll
    for (int kk = 0; kk < 256; kk += 32) {
      bf16x8 bfr[4];
      if (kk < 128) {
#pragma unroll
        for (int n = 0; n < 4; ++n)
          bfr[n] = *(const bf16x8*)(h + (growbase + wr + n*16 + l15)*128 + kk + 8*g);
      } else {
#pragma unroll
        for (int n = 0; n < 4; ++n) {
          int lr = wr + n*16 + l15;
          int kl = (kk - 128) + 8*g;
          bfr[n] = *(const bf16x8*)(aggs + lr*128 + (kl ^ ((lr & 7) << 3)));
        }
      }
      bf16x8 wfr[4];
#pragma unroll
      for (int m = 0; m < 4; ++m) {
        int c = wc + m*16 + l15;
        wfr[m] = *(const bf16x8*)(WTu + c*256 + ((kk + 8*g) ^ ((c & 7) << 3)));
      }
#pragma unroll
      for (int m = 0; m < 4; ++m)
#pragma unroll
        for (int n = 0; n < 4; ++n)
          acc[m][n] = __builtin_amdgcn_mfma_f32_16x16x32_bf16(wfr[m], bfr[n], acc[m][n], 0,0,0);
    }
    __syncthreads();  // all h reads (cross-wave cols) + aggs reads drained
#pragma unroll
    for (int m = 0; m < 4; ++m) {
      f32x4 bs = *(const f32x4*)(bu + wc + m*16 + g*4);
#pragma unroll
      for (int n = 0; n < 4; ++n) {
        int lr = wr + n*16 + l15;
        size_t r = growbase + lr;
        float mv = mask[r];
        bf16x4 o;
#pragma unroll
        for (int j = 0; j < 4; ++j)
          o[j] = (bf16)(fmaxf(acc[m][n][j] + bs[j], 0.f) * mv);
        int c0 = wc + m*16 + g*4;
        *(bf16x4*)(h + r*128 + c0) = o;
        if (DO_MSG)
          *(bf16x4*)(htile + lr*128 + (c0 ^ ((lr & 7) << 3))) = o;
      }
    }
  }
  if (!DO_MSG) return;
  __syncthreads();   // htile visible

  // ================= Phase C: msgTout = relu(h_new @ Wm + bm)^T
  {
    f32x4 acc[4][4];
#pragma unroll
    for (int m = 0; m < 4; ++m)
#pragma unroll
      for (int n = 0; n < 4; ++n) acc[m][n] = (f32x4){0.f,0.f,0.f,0.f};
#pragma unroll
    for (int kk = 0; kk < 128; kk += 32) {
      bf16x8 bfr[4], wfr[4];
#pragma unroll
      for (int n = 0; n < 4; ++n) {
        int lr = wr + n*16 + l15;
        bfr[n] = *(const bf16x8*)(htile + lr*128 + ((kk + 8*g) ^ ((lr & 7) << 3)));
      }
#pragma unroll
      for (int m = 0; m < 4; ++m) {
        int c = wc + m*16 + l15;
        wfr[m] = *(const bf16x8*)(WTm + c*128 + ((kk + 8*g) ^ ((c & 7) << 3)));
      }
#pragma unroll
      for (int m = 0; m < 4; ++m)
#pragma unroll
        for (int n = 0; n < 4; ++n)
          acc[m][n] = __builtin_amdgcn_mfma_f32_16x16x32_bf16(bfr[n], wfr[m], acc[m][n], 0,0,0);
    }
#pragma unroll
    for (int m = 0; m < 4; ++m) {
      int c = wc + m*16 + l15;
      float bc = bm[c];
#pragma unroll
      for (int n = 0; n < 4; ++n) {
        int rl = i0 + wr + n*16 + g*4;
        bf16x4 o;
#pragma unroll
        for (int j = 0; j < 4; ++j) o[j] = (bf16)fmaxf(acc[m][n][j] + bc, 0.f);
        *(bf16x4*)(msgTout + ((size_t)(b*128 + c))*512 + rl) = o;
      }
    }
  }
}

// -------------------------------------------------- fused pool + readout
__global__ __launch_bounds__(256) void pool_readout(
    const bf16* __restrict__ h, const float* __restrict__ mask,
    const float* __restrict__ W1, const float* __restrict__ b1,
    const float* __restrict__ W2, const float* __restrict__ b2,
    float* __restrict__ out) {
  __shared__ float part[3][128];
  __shared__ float pl[128];
  __shared__ float hid[128];
  int b = blockIdx.x, t = threadIdx.x, g = t >> 6, cp = (t & 63)*2;
  float a0 = 0.f, a1 = 0.f;
  for (int n = g*128; n < g*128+128; ++n) {
    float mv = mask[(size_t)b*Nn + n];
    bf16x2 v = *(const bf16x2*)(h + ((size_t)b*Nn + n)*128 + cp);
    a0 = fmaf((float)v[0], mv, a0);
    a1 = fmaf((float)v[1], mv, a1);
  }
  if (g > 0) { part[g-1][cp] = a0; part[g-1][cp+1] = a1; }
  __syncthreads();
  if (g == 0) {
    pl[cp]   = a0 + part[0][cp]   + part[1][cp]   + part[2][cp];
    pl[cp+1] = a1 + part[0][cp+1] + part[1][cp+1] + part[2][cp+1];
  }
  __syncthreads();
  if (t < 128) {
    float a = b1[t];
#pragma unroll 4
    for (int j = 0; j < 128; ++j) a = fmaf(pl[j], W1[j*128 + t], a);
    hid[t] = fmaxf(a, 0.f);
  }
  __syncthreads();
  if (t < 128) {
    float a = b2[t];
#pragma unroll 4
    for (int j = 0; j < 128; ++j) a = fmaf(hid[j], W2[j*128 + t], a);
    out[(size_t)b*128 + t] = a;
  }
}

// -------------------------------------------------- launch
extern "C" void kernel_launch(void* const* d_in, const int* in_sizes, int n_in,
                              void* d_out, int out_size, void* d_ws, size_t ws_size,
                              hipStream_t stream) {
  const float* jets = (const float*)d_in[0];
  const float* mask = (const float*)d_in[1];
  const float* eW0  = (const float*)d_in[2];
  const float* eb0  = (const float*)d_in[3];
  const float* eW1  = (const float*)d_in[4];
  const float* eb1  = (const float*)d_in[5];
  const float* Wm   = (const float*)d_in[6];
  const float* bm   = (const float*)d_in[7];
  const float* Wu   = (const float*)d_in[8];
  const float* bu   = (const float*)d_in[9];
  const float* rW1  = (const float*)d_in[10];
  const float* rb1  = (const float*)d_in[11];
  const float* rW2  = (const float*)d_in[12];
  const float* rb2  = (const float*)d_in[13];
  float* out = (float*)d_out;

  bf16* h     = (bf16*)d_ws;                    // ROWS*128
  bf16* msgTA = h     + (size_t)ROWS*128;       // ROWS*128 (layout [b][c][n])
  bf16* msgTB = msgTA + (size_t)ROWS*128;       // ROWS*128 (ping-pong)
  bf16* P     = msgTB + (size_t)ROWS*128;       // Bb*512*512 (67 MB, bf16 E)
  bf16* WTe   = P     + (size_t)Bb*512*512;     // 128*128
  bf16* WTm   = WTe   + 128*128;                // 3*128*128
  bf16* WTu   = WTm   + 3*128*128;              // 3*256*128
  float* rsum = (float*)(WTu + 3*256*128);      // ROWS (1/l_i)

  prep_all<<<640, 256, 0, stream>>>(eW1, Wm, Wu, WTe, WTm, WTu);
  pmat_kernel<<<Bb*4, 256, 0, stream>>>(jets, mask, P, rsum);
  embed_msg0<<<ROWS/128, 256, 0, stream>>>(jets, eW0, eb0, WTe, eb1,
                                           WTm, bm, h, msgTA);
  // iter 0: msgTA -> msgTB
  iter_fused<true><<<Bb*4, 256, 0, stream>>>(
      P, rsum, mask, msgTA, h,
      WTu, bu, WTm + (size_t)1*128*128, bm + 1*128, msgTB);
  // iter 1: msgTB -> msgTA
  iter_fused<true><<<Bb*4, 256, 0, stream>>>(
      P, rsum, mask, msgTB, h,
      WTu + (size_t)1*256*128, bu + 1*128,
      WTm + (size_t)2*128*128, bm + 2*128, msgTA);
  // iter 2 (no next msg): reads msgTA
  iter_fused<false><<<Bb*4, 256, 0, stream>>>(
      P, rsum, mask, msgTA, h,
      WTu + (size_t)2*256*128, bu + 2*128, nullptr, nullptr, nullptr);

  pool_readout<<<Bb, 256, 0, stream>>>(h, mask, rW1, rb1, rW2, rb2, out);
}

// Round 13
// 231.003 us; speedup vs baseline: 1.0037x; 1.0037x over previous
//
#include <hip/hip_runtime.h>
#include <stdint.h>
#include <stddef.h>

#define Bb 128
#define Nn 512
#define Hh 128
#define ROWS (Bb*Nn)

typedef __bf16 bf16;
typedef __bf16 bf16x2 __attribute__((ext_vector_type(2)));
typedef __bf16 bf16x4 __attribute__((ext_vector_type(4)));
typedef __bf16 bf16x8 __attribute__((ext_vector_type(8)));
typedef float  f32x4  __attribute__((ext_vector_type(4)));

__device__ __forceinline__ void glds16(const void* g, void* l) {
  __builtin_amdgcn_global_load_lds(
      (const __attribute__((address_space(1))) void*)g,
      (__attribute__((address_space(3))) void*)l, 16, 0, 0);
}

// -------------------------------------------------- weight prep (all in one)
// fp32 W[k][c] -> bf16 W^T[c][k ^ ((c&7)<<3)]  (swizzle pre-applied)
__global__ __launch_bounds__(256) void prep_all(
    const float* __restrict__ eW1, const float* __restrict__ Wm,
    const float* __restrict__ Wu, bf16* __restrict__ WTe,
    bf16* __restrict__ WTm, bf16* __restrict__ WTu) {
  int idx = blockIdx.x*256 + threadIdx.x;
  if (idx < 16384) {                       // eW1: 128x128
    int k = idx >> 7, c = idx & 127;
    WTe[c*128 + (k ^ ((c & 7) << 3))] = (bf16)eW1[idx];
  } else if (idx < 16384 + 49152) {        // Wm: 3x128x128
    int sub = idx - 16384;
    int m = sub >> 14, r = sub & 16383;
    int k = r >> 7, c = r & 127;
    WTm[m*16384 + c*128 + (k ^ ((c & 7) << 3))] = (bf16)Wm[sub];
  } else if (idx < 16384 + 49152 + 98304) { // Wu: 3x256x128
    int sub = idx - 65536;
    int m = sub >> 15, r = sub & 32767;
    int k = r >> 7, c = r & 127;
    WTu[m*32768 + c*256 + (k ^ ((c & 7) << 3))] = (bf16)Wu[sub];
  }
}

// -------------------------------------------------- P materialization (once)
// E_ij = exp(2 x_i.x_j - |x_j|^2 - pen_j - |x_i|^2) in (0,1], stored bf16
// UNNORMALIZED in row-major P[b][i][j]; rsum = 1/sum_j E.
__global__ __launch_bounds__(256) void pmat_kernel(
    const float* __restrict__ jets, const float* __restrict__ mask,
    bf16* __restrict__ P, float* __restrict__ rsum) {
  __shared__ float Xs[Nn*9];
  __shared__ float cbs[Nn];
  const int t = threadIdx.x;
  const int b = blockIdx.x & 127, ic = blockIdx.x >> 7;
  const int i0 = ic*128;
  const float* jb = jets + (size_t)b*Nn*8;
  for (int j = t; j < Nn; j += 256) {
    float s2 = 0.f;
#pragma unroll
    for (int f = 0; f < 8; ++f) { float v = jb[j*8+f]; Xs[j*9+f] = v; s2 = fmaf(v,v,s2); }
    cbs[j] = s2 + (mask[(size_t)b*Nn+j] > 0.f ? 0.f : 1e9f);
  }
  __syncthreads();
  const int w = t >> 6, lane = t & 63, l15 = lane & 15, g = lane >> 4;
  const int i0w = i0 + w*32;
  float xi2[2][8], sqi[2], lsum[2];
#pragma unroll
  for (int r = 0; r < 2; ++r) {
    int i = i0w + r*16 + l15;
    float sq = 0.f;
#pragma unroll
    for (int f = 0; f < 8; ++f) {
      float v = Xs[i*9+f];
      xi2[r][f] = 2.f*v;
      sq = fmaf(v, v, sq);
    }
    sqi[r] = sq;
    lsum[r] = 0.f;
  }
  bf16* Pr[2];
#pragma unroll
  for (int r = 0; r < 2; ++r)
    Pr[r] = P + ((size_t)(b*512) + i0w + r*16 + l15)*512 + 8*g;
#pragma unroll 2
  for (int j0 = 0; j0 < Nn; j0 += 32) {
    bf16x8 pfr[2];
#pragma unroll
    for (int e = 0; e < 8; ++e) {
      int j = j0 + 8*g + e;
      float xj[8];
#pragma unroll
      for (int f = 0; f < 8; ++f) xj[f] = Xs[j*9+f];
      float cb = cbs[j];
      float d0 = -(cb + sqi[0]);
      float d1 = -(cb + sqi[1]);
#pragma unroll
      for (int f = 0; f < 8; ++f) {
        d0 = fmaf(xi2[0][f], xj[f], d0);
        d1 = fmaf(xi2[1][f], xj[f], d1);
      }
      float ev0 = __expf(d0), ev1 = __expf(d1);
      lsum[0] += ev0; lsum[1] += ev1;
      pfr[0][e] = (bf16)ev0;
      pfr[1][e] = (bf16)ev1;
    }
#pragma unroll
    for (int r = 0; r < 2; ++r)
      *(bf16x8*)(Pr[r] + j0) = pfr[r];
  }
#pragma unroll
  for (int r = 0; r < 2; ++r) {
    float s = lsum[r];
    s += __shfl_xor(s, 16, 64);
    s += __shfl_xor(s, 32, 64);
    if (g == 0) rsum[(size_t)b*Nn + i0w + r*16 + l15] = 1.f/s;
  }
}

// -------------------------------------------------- fused embed L1+L2+msg0
__global__ __launch_bounds__(256) void embed_msg0(
    const float* __restrict__ jets, const float* __restrict__ W0,
    const float* __restrict__ b0, const bf16* __restrict__ WTe,
    const float* __restrict__ b1, const bf16* __restrict__ WTm0,
    const float* __restrict__ bm0, bf16* __restrict__ h,
    bf16* __restrict__ msgT) {
  __shared__ float sW0[8*128];
  __shared__ float sb0[128];
  __shared__ bf16 h0s[128*128];   // swizzled; reused for h-tile later
  __shared__ bf16 sWT[128*128];   // swizzled W1^T
  const int t = threadIdx.x;
  const int w = t >> 6, lane = t & 63, l15 = lane & 15, g = lane >> 4;
  const int row_blk = blockIdx.x*128;
  for (int q = w; q < 32; q += 4)
    glds16((const char*)WTe + q*1024 + lane*16, (char*)(void*)sWT + q*1024);
  for (int i = t; i < 8*128; i += 256) sW0[i] = W0[i];
  if (t < 128) sb0[t] = b0[t];
  __syncthreads();
  // layer 1: thread owns 1 row, 64 cols
  {
    const int row = t & 127, colbase = (t >> 7) * 64;
    const float4* jp = (const float4*)(jets + ((size_t)row_blk + row)*8);
    float4 x0 = jp[0], x1 = jp[1];
    float x[8] = {x0.x,x0.y,x0.z,x0.w,x1.x,x1.y,x1.z,x1.w};
    const int sw = (row & 7) << 3;
#pragma unroll
    for (int cg = 0; cg < 16; ++cg) {
      int c0 = colbase + cg*4;
      bf16x4 o;
#pragma unroll
      for (int j = 0; j < 4; ++j) {
        float a = sb0[c0+j];
#pragma unroll
        for (int f = 0; f < 8; ++f) a = fmaf(x[f], sW0[f*128 + c0 + j], a);
        o[j] = (bf16)fmaxf(a, 0.f);
      }
      *(bf16x4*)(h0s + row*128 + (c0 ^ sw)) = o;
    }
  }
  __syncthreads();
  // layer 2: MFMA, 4 waves 2x2
  const int wr = (w & 1)*64, wc = (w >> 1)*64;
  f32x4 acc[4][4];
#pragma unroll
  for (int m = 0; m < 4; ++m)
#pragma unroll
    for (int n = 0; n < 4; ++n) acc[m][n] = (f32x4){0.f,0.f,0.f,0.f};
#pragma unroll
  for (int kk = 0; kk < 128; kk += 32) {
    bf16x8 bfr[4], wfr[4];
#pragma unroll
    for (int n = 0; n < 4; ++n) {
      int row = wr + n*16 + l15;
      bfr[n] = *(const bf16x8*)(h0s + row*128 + ((kk + 8*g) ^ ((row & 7) << 3)));
    }
#pragma unroll
    for (int m = 0; m < 4; ++m) {
      int c = wc + m*16 + l15;
      wfr[m] = *(const bf16x8*)(sWT + c*128 + ((kk + 8*g) ^ ((c & 7) << 3)));
    }
#pragma unroll
    for (int m = 0; m < 4; ++m)
#pragma unroll
      for (int n = 0; n < 4; ++n)
        acc[m][n] = __builtin_amdgcn_mfma_f32_16x16x32_bf16(wfr[m], bfr[n], acc[m][n], 0,0,0);
  }
  __syncthreads();   // everyone done reading h0s before overwrite
#pragma unroll
  for (int m = 0; m < 4; ++m) {
    f32x4 bs = *(const f32x4*)(b1 + wc + m*16 + g*4);
#pragma unroll
    for (int n = 0; n < 4; ++n) {
      int lr = wr + n*16 + l15;
      int r = row_blk + lr;
      int c0 = wc + m*16 + g*4;
      bf16x4 o;
#pragma unroll
      for (int j = 0; j < 4; ++j) o[j] = (bf16)fmaxf(acc[m][n][j] + bs[j], 0.f);
      *(bf16x4*)(h + (size_t)r*128 + c0) = o;
      *(bf16x4*)(h0s + lr*128 + (c0 ^ ((lr & 7) << 3))) = o;
    }
  }
  __syncthreads();
  // msg0: msgT = relu(htile @ Wm0 + bm0), TRANSOUT; Wm0 frags from global(L2)
  {
    f32x4 acc2[4][4];
#pragma unroll
    for (int m = 0; m < 4; ++m)
#pragma unroll
      for (int n = 0; n < 4; ++n) acc2[m][n] = (f32x4){0.f,0.f,0.f,0.f};
#pragma unroll
    for (int kk = 0; kk < 128; kk += 32) {
      bf16x8 bfr[4], wfr[4];
#pragma unroll
      for (int n = 0; n < 4; ++n) {
        int lr = wr + n*16 + l15;
        bfr[n] = *(const bf16x8*)(h0s + lr*128 + ((kk + 8*g) ^ ((lr & 7) << 3)));
      }
#pragma unroll
      for (int m = 0; m < 4; ++m) {
        int c = wc + m*16 + l15;
        wfr[m] = *(const bf16x8*)(WTm0 + c*128 + ((kk + 8*g) ^ ((c & 7) << 3)));
      }
#pragma unroll
      for (int m = 0; m < 4; ++m)
#pragma unroll
        for (int n = 0; n < 4; ++n)
          acc2[m][n] = __builtin_amdgcn_mfma_f32_16x16x32_bf16(bfr[n], wfr[m], acc2[m][n], 0,0,0);
    }
    const int b = row_blk >> 9;
    const int rbase = (row_blk & 511) + wr;
#pragma unroll
    for (int m = 0; m < 4; ++m) {
      int c = wc + m*16 + l15;
      float bc = bm0[c];
#pragma unroll
      for (int n = 0; n < 4; ++n) {
        int rl = rbase + n*16 + g*4;
        bf16x4 o;
#pragma unroll
        for (int j = 0; j < 4; ++j) o[j] = (bf16)fmaxf(acc2[m][n][j] + bc, 0.f);
        *(bf16x4*)(msgT + ((size_t)(b*128 + c))*512 + rl) = o;
      }
    }
  }
}

// -------------------------------------------------- fused per-iteration kernel
// Phase A: pure GEMM on materialized P with EXPLICIT 2-stage double-buffered
// load clusters (8 afr + 2 pfr batched -> one wait -> 16 MFMA), so the memory
// pipeline keeps ~10 loads in flight instead of serializing at low VGPR.
// Phase B: h_new = relu([h|agg]@Wu+bu)*mask (in-place h).
// Phase C (DO_MSG): msgTout = relu(h_new@Wm+bm)^T. msgTin != msgTout.
template<bool DO_MSG>
__global__ __launch_bounds__(256) void iter_fused(
    const bf16* __restrict__ P, const float* __restrict__ rsum,
    const float* __restrict__ mask, const bf16* __restrict__ msgTin,
    bf16* __restrict__ h,
    const bf16* __restrict__ WTu, const float* __restrict__ bu,
    const bf16* __restrict__ WTm, const float* __restrict__ bm,
    bf16* __restrict__ msgTout) {
  __shared__ __align__(16) char smem[65536];
  bf16* htile = (bf16*)smem;                 // [128][128] 32KB
  bf16* aggs  = (bf16*)(smem + 32768);       // [128][128] 32KB
  const int t = threadIdx.x;
  const int b  = blockIdx.x & 127;
  const int ic = blockIdx.x >> 7;             // 0..3
  const int i0 = ic*128;
  const int w = t >> 6, lane = t & 63, l15 = lane & 15, g = lane >> 4;

  // ================= Phase A: agg rows i0 + w*32 .. +31 (pipelined pure GEMM)
  {
    const int i0w = i0 + w*32;
    float r_i[2];
#pragma unroll
    for (int r = 0; r < 2; ++r) r_i[r] = rsum[(size_t)b*Nn + i0w + r*16 + l15];
    f32x4 acc[2][8];
#pragma unroll
    for (int r = 0; r < 2; ++r)
#pragma unroll
      for (int m = 0; m < 8; ++m) acc[r][m] = (f32x4){0.f,0.f,0.f,0.f};
    const bf16* mB  = msgTin + (size_t)b*128*512 + (size_t)l15*512 + 8*g;
    const bf16* pB0 = P + ((size_t)(b*512) + i0w + l15)*512 + 8*g;
    const bf16* pB1 = pB0 + (size_t)16*512;

    bf16x8 afrA[8], afrB[8], pfrA[2], pfrB[2];
    auto loadA = [&](int J) {
#pragma unroll
      for (int m = 0; m < 8; ++m) afrA[m] = *(const bf16x8*)(mB + m*8192 + J);
      pfrA[0] = *(const bf16x8*)(pB0 + J);
      pfrA[1] = *(const bf16x8*)(pB1 + J);
    };
    auto loadB = [&](int J) {
#pragma unroll
      for (int m = 0; m < 8; ++m) afrB[m] = *(const bf16x8*)(mB + m*8192 + J);
      pfrB[0] = *(const bf16x8*)(pB0 + J);
      pfrB[1] = *(const bf16x8*)(pB1 + J);
    };
    auto compute = [&](const bf16x8* afr, const bf16x8* pfr) {
#pragma unroll
      for (int m = 0; m < 8; ++m) {
        acc[0][m] = __builtin_amdgcn_mfma_f32_16x16x32_bf16(afr[m], pfr[0], acc[0][m], 0,0,0);
        acc[1][m] = __builtin_amdgcn_mfma_f32_16x16x32_bf16(afr[m], pfr[1], acc[1][m], 0,0,0);
      }
    };

    loadA(0);
#pragma unroll
    for (int jj = 0; jj < Nn; jj += 64) {
      loadB(jj + 32);
      compute(afrA, pfrA);
      if (jj + 64 < Nn) loadA(jj + 64);
      compute(afrB, pfrB);
    }
    // epilogue -> aggs LDS (swizzled), normalized by r_i
#pragma unroll
    for (int r = 0; r < 2; ++r) {
      int lr = w*32 + r*16 + l15;      // local row 0..127
#pragma unroll
      for (int m = 0; m < 8; ++m) {
        bf16x4 o;
#pragma unroll
        for (int j = 0; j < 4; ++j) o[j] = (bf16)(acc[r][m][j] * r_i[r]);
        int c0 = m*16 + g*4;
        *(bf16x4*)(aggs + lr*128 + (c0 ^ ((lr & 7) << 3))) = o;
      }
    }
  }
  __syncthreads();   // aggs visible to all waves

  // ================= Phase B: h_new = relu([h|agg] @ Wu + bu) * mask
  const int wr = (w & 1)*64, wc = (w >> 1)*64;
  const size_t growbase = (size_t)b*Nn + i0;
  {
    f32x4 acc[4][4];
#pragma unroll
    for (int m = 0; m < 4; ++m)
#pragma unroll
      for (int n = 0; n < 4; ++n) acc[m][n] = (f32x4){0.f,0.f,0.f,0.f};
#pragma unroll
    for (int kk = 0; kk < 256; kk += 32) {
      bf16x8 bfr[4];
      if (kk < 128) {
#pragma unroll
        for (int n = 0; n < 4; ++n)
          bfr[n] = *(const bf16x8*)(h + (growbase + wr + n*16 + l15)*128 + kk + 8*g);
      } else {
#pragma unroll
        for (int n = 0; n < 4; ++n) {
          int lr = wr + n*16 + l15;
          int kl = (kk - 128) + 8*g;
          bfr[n] = *(const bf16x8*)(aggs + lr*128 + (kl ^ ((lr & 7) << 3)));
        }
      }
      bf16x8 wfr[4];
#pragma unroll
      for (int m = 0; m < 4; ++m) {
        int c = wc + m*16 + l15;
        wfr[m] = *(const bf16x8*)(WTu + c*256 + ((kk + 8*g) ^ ((c & 7) << 3)));
      }
#pragma unroll
      for (int m = 0; m < 4; ++m)
#pragma unroll
        for (int n = 0; n < 4; ++n)
          acc[m][n] = __builtin_amdgcn_mfma_f32_16x16x32_bf16(wfr[m], bfr[n], acc[m][n], 0,0,0);
    }
    __syncthreads();  // all h reads (cross-wave cols) + aggs reads drained
#pragma unroll
    for (int m = 0; m < 4; ++m) {
      f32x4 bs = *(const f32x4*)(bu + wc + m*16 + g*4);
#pragma unroll
      for (int n = 0; n < 4; ++n) {
        int lr = wr + n*16 + l15;
        size_t r = growbase + lr;
        float mv = mask[r];
        bf16x4 o;
#pragma unroll
        for (int j = 0; j < 4; ++j)
          o[j] = (bf16)(fmaxf(acc[m][n][j] + bs[j], 0.f) * mv);
        int c0 = wc + m*16 + g*4;
        *(bf16x4*)(h + r*128 + c0) = o;
        if (DO_MSG)
          *(bf16x4*)(htile + lr*128 + (c0 ^ ((lr & 7) << 3))) = o;
      }
    }
  }
  if (!DO_MSG) return;
  __syncthreads();   // htile visible

  // ================= Phase C: msgTout = relu(h_new @ Wm + bm)^T
  {
    f32x4 acc[4][4];
#pragma unroll
    for (int m = 0; m < 4; ++m)
#pragma unroll
      for (int n = 0; n < 4; ++n) acc[m][n] = (f32x4){0.f,0.f,0.f,0.f};
#pragma unroll
    for (int kk = 0; kk < 128; kk += 32) {
      bf16x8 bfr[4], wfr[4];
#pragma unroll
      for (int n = 0; n < 4; ++n) {
        int lr = wr + n*16 + l15;
        bfr[n] = *(const bf16x8*)(htile + lr*128 + ((kk + 8*g) ^ ((lr & 7) << 3)));
      }
#pragma unroll
      for (int m = 0; m < 4; ++m) {
        int c = wc + m*16 + l15;
        wfr[m] = *(const bf16x8*)(WTm + c*128 + ((kk + 8*g) ^ ((c & 7) << 3)));
      }
#pragma unroll
      for (int m = 0; m < 4; ++m)
#pragma unroll
        for (int n = 0; n < 4; ++n)
          acc[m][n] = __builtin_amdgcn_mfma_f32_16x16x32_bf16(bfr[n], wfr[m], acc[m][n], 0,0,0);
    }
#pragma unroll
    for (int m = 0; m < 4; ++m) {
      int c = wc + m*16 + l15;
      float bc = bm[c];
#pragma unroll
      for (int n = 0; n < 4; ++n) {
        int rl = i0 + wr + n*16 + g*4;
        bf16x4 o;
#pragma unroll
        for (int j = 0; j < 4; ++j) o[j] = (bf16)fmaxf(acc[m][n][j] + bc, 0.f);
        *(bf16x4*)(msgTout + ((size_t)(b*128 + c))*512 + rl) = o;
      }
    }
  }
}

// -------------------------------------------------- fused pool + readout
__global__ __launch_bounds__(256) void pool_readout(
    const bf16* __restrict__ h, const float* __restrict__ mask,
    const float* __restrict__ W1, const float* __restrict__ b1,
    const float* __restrict__ W2, const float* __restrict__ b2,
    float* __restrict__ out) {
  __shared__ float part[3][128];
  __shared__ float pl[128];
  __shared__ float hid[128];
  int b = blockIdx.x, t = threadIdx.x, g = t >> 6, cp = (t & 63)*2;
  float a0 = 0.f, a1 = 0.f;
  for (int n = g*128; n < g*128+128; ++n) {
    float mv = mask[(size_t)b*Nn + n];
    bf16x2 v = *(const bf16x2*)(h + ((size_t)b*Nn + n)*128 + cp);
    a0 = fmaf((float)v[0], mv, a0);
    a1 = fmaf((float)v[1], mv, a1);
  }
  if (g > 0) { part[g-1][cp] = a0; part[g-1][cp+1] = a1; }
  __syncthreads();
  if (g == 0) {
    pl[cp]   = a0 + part[0][cp]   + part[1][cp]   + part[2][cp];
    pl[cp+1] = a1 + part[0][cp+1] + part[1][cp+1] + part[2][cp+1];
  }
  __syncthreads();
  if (t < 128) {
    float a = b1[t];
#pragma unroll 4
    for (int j = 0; j < 128; ++j) a = fmaf(pl[j], W1[j*128 + t], a);
    hid[t] = fmaxf(a, 0.f);
  }
  __syncthreads();
  if (t < 128) {
    float a = b2[t];
#pragma unroll 4
    for (int j = 0; j < 128; ++j) a = fmaf(hid[j], W2[j*128 + t], a);
    out[(size_t)b*128 + t] = a;
  }
}

// -------------------------------------------------- launch
extern "C" void kernel_launch(void* const* d_in, const int* in_sizes, int n_in,
                              void* d_out, int out_size, void* d_ws, size_t ws_size,
                              hipStream_t stream) {
  const float* jets = (const float*)d_in[0];
  const float* mask = (const float*)d_in[1];
  const float* eW0  = (const float*)d_in[2];
  const float* eb0  = (const float*)d_in[3];
  const float* eW1  = (const float*)d_in[4];
  const float* eb1  = (const float*)d_in[5];
  const float* Wm   = (const float*)d_in[6];
  const float* bm   = (const float*)d_in[7];
  const float* Wu   = (const float*)d_in[8];
  const float* bu   = (const float*)d_in[9];
  const float* rW1  = (const float*)d_in[10];
  const float* rb1  = (const float*)d_in[11];
  const float* rW2  = (const float*)d_in[12];
  const float* rb2  = (const float*)d_in[13];
  float* out = (float*)d_out;

  bf16* h     = (bf16*)d_ws;                    // ROWS*128
  bf16* msgTA = h     + (size_t)ROWS*128;       // ROWS*128 (layout [b][c][n])
  bf16* msgTB = msgTA + (size_t)ROWS*128;       // ROWS*128 (ping-pong)
  bf16* P     = msgTB + (size_t)ROWS*128;       // Bb*512*512 (67 MB, bf16 E)
  bf16* WTe   = P     + (size_t)Bb*512*512;     // 128*128
  bf16* WTm   = WTe   + 128*128;                // 3*128*128
  bf16* WTu   = WTm   + 3*128*128;              // 3*256*128
  float* rsum = (float*)(WTu + 3*256*128);      // ROWS (1/l_i)

  prep_all<<<640, 256, 0, stream>>>(eW1, Wm, Wu, WTe, WTm, WTu);
  pmat_kernel<<<Bb*4, 256, 0, stream>>>(jets, mask, P, rsum);
  embed_msg0<<<ROWS/128, 256, 0, stream>>>(jets, eW0, eb0, WTe, eb1,
                                           WTm, bm, h, msgTA);
  // iter 0: msgTA -> msgTB
  iter_fused<true><<<Bb*4, 256, 0, stream>>>(
      P, rsum, mask, msgTA, h,
      WTu, bu, WTm + (size_t)1*128*128, bm + 1*128, msgTB);
  // iter 1: msgTB -> msgTA
  iter_fused<true><<<Bb*4, 256, 0, stream>>>(
      P, rsum, mask, msgTB, h,
      WTu + (size_t)1*256*128, bu + 1*128,
      WTm + (size_t)2*128*128, bm + 2*128, msgTA);
  // iter 2 (no next msg): reads msgTA
  iter_fused<false><<<Bb*4, 256, 0, stream>>>(
      P, rsum, mask, msgTA, h,
      WTu + (size_t)2*256*128, bu + 2*128, nullptr, nullptr, nullptr);

  pool_readout<<<Bb, 256, 0, stream>>>(h, mask, rW1, rb1, rW2, rb2, out);
}

// Round 14
// 230.941 us; speedup vs baseline: 1.0040x; 1.0003x over previous
//
#include <hip/hip_runtime.h>
#include <stdint.h>
#include <stddef.h>

#define Bb 128
#define Nn 512
#define Hh 128
#define ROWS (Bb*Nn)

typedef __bf16 bf16;
typedef __bf16 bf16x2 __attribute__((ext_vector_type(2)));
typedef __bf16 bf16x4 __attribute__((ext_vector_type(4)));
typedef __bf16 bf16x8 __attribute__((ext_vector_type(8)));
typedef float  f32x4  __attribute__((ext_vector_type(4)));

__device__ __forceinline__ void glds16(const void* g, void* l) {
  __builtin_amdgcn_global_load_lds(
      (const __attribute__((address_space(1))) void*)g,
      (__attribute__((address_space(3))) void*)l, 16, 0, 0);
}

// -------------------------------------------------- weight prep (all in one)
// fp32 W[k][c] -> bf16 W^T[c][k ^ ((c&7)<<3)]  (swizzle pre-applied)
__global__ __launch_bounds__(256) void prep_all(
    const float* __restrict__ eW1, const float* __restrict__ Wm,
    const float* __restrict__ Wu, bf16* __restrict__ WTe,
    bf16* __restrict__ WTm, bf16* __restrict__ WTu) {
  int idx = blockIdx.x*256 + threadIdx.x;
  if (idx < 16384) {                       // eW1: 128x128
    int k = idx >> 7, c = idx & 127;
    WTe[c*128 + (k ^ ((c & 7) << 3))] = (bf16)eW1[idx];
  } else if (idx < 16384 + 49152) {        // Wm: 3x128x128
    int sub = idx - 16384;
    int m = sub >> 14, r = sub & 16383;
    int k = r >> 7, c = r & 127;
    WTm[m*16384 + c*128 + (k ^ ((c & 7) << 3))] = (bf16)Wm[sub];
  } else if (idx < 16384 + 49152 + 98304) { // Wu: 3x256x128
    int sub = idx - 65536;
    int m = sub >> 15, r = sub & 32767;
    int k = r >> 7, c = r & 127;
    WTu[m*32768 + c*256 + (k ^ ((c & 7) << 3))] = (bf16)Wu[sub];
  }
}

// -------------------------------------------------- P materialization (once)
// E_ij = exp(2 x_i.x_j - |x_j|^2 - pen_j - |x_i|^2) in (0,1], stored bf16
// UNNORMALIZED in row-major P[b][i][j]; rsum = 1/sum_j E.
__global__ __launch_bounds__(256) void pmat_kernel(
    const float* __restrict__ jets, const float* __restrict__ mask,
    bf16* __restrict__ P, float* __restrict__ rsum) {
  __shared__ float Xs[Nn*9];
  __shared__ float cbs[Nn];
  const int t = threadIdx.x;
  const int b = blockIdx.x & 127, ic = blockIdx.x >> 7;
  const int i0 = ic*128;
  const float* jb = jets + (size_t)b*Nn*8;
  for (int j = t; j < Nn; j += 256) {
    float s2 = 0.f;
#pragma unroll
    for (int f = 0; f < 8; ++f) { float v = jb[j*8+f]; Xs[j*9+f] = v; s2 = fmaf(v,v,s2); }
    cbs[j] = s2 + (mask[(size_t)b*Nn+j] > 0.f ? 0.f : 1e9f);
  }
  __syncthreads();
  const int w = t >> 6, lane = t & 63, l15 = lane & 15, g = lane >> 4;
  const int i0w = i0 + w*32;
  float xi2[2][8], sqi[2], lsum[2];
#pragma unroll
  for (int r = 0; r < 2; ++r) {
    int i = i0w + r*16 + l15;
    float sq = 0.f;
#pragma unroll
    for (int f = 0; f < 8; ++f) {
      float v = Xs[i*9+f];
      xi2[r][f] = 2.f*v;
      sq = fmaf(v, v, sq);
    }
    sqi[r] = sq;
    lsum[r] = 0.f;
  }
  bf16* Pr[2];
#pragma unroll
  for (int r = 0; r < 2; ++r)
    Pr[r] = P + ((size_t)(b*512) + i0w + r*16 + l15)*512 + 8*g;
#pragma unroll 2
  for (int j0 = 0; j0 < Nn; j0 += 32) {
    bf16x8 pfr[2];
#pragma unroll
    for (int e = 0; e < 8; ++e) {
      int j = j0 + 8*g + e;
      float xj[8];
#pragma unroll
      for (int f = 0; f < 8; ++f) xj[f] = Xs[j*9+f];
      float cb = cbs[j];
      float d0 = -(cb + sqi[0]);
      float d1 = -(cb + sqi[1]);
#pragma unroll
      for (int f = 0; f < 8; ++f) {
        d0 = fmaf(xi2[0][f], xj[f], d0);
        d1 = fmaf(xi2[1][f], xj[f], d1);
      }
      float ev0 = __expf(d0), ev1 = __expf(d1);
      lsum[0] += ev0; lsum[1] += ev1;
      pfr[0][e] = (bf16)ev0;
      pfr[1][e] = (bf16)ev1;
    }
#pragma unroll
    for (int r = 0; r < 2; ++r)
      *(bf16x8*)(Pr[r] + j0) = pfr[r];
  }
#pragma unroll
  for (int r = 0; r < 2; ++r) {
    float s = lsum[r];
    s += __shfl_xor(s, 16, 64);
    s += __shfl_xor(s, 32, 64);
    if (g == 0) rsum[(size_t)b*Nn + i0w + r*16 + l15] = 1.f/s;
  }
}

// -------------------------------------------------- fused embed L1+L2+msg0
__global__ __launch_bounds__(256) void embed_msg0(
    const float* __restrict__ jets, const float* __restrict__ W0,
    const float* __restrict__ b0, const bf16* __restrict__ WTe,
    const float* __restrict__ b1, const bf16* __restrict__ WTm0,
    const float* __restrict__ bm0, bf16* __restrict__ h,
    bf16* __restrict__ msgT) {
  __shared__ float sW0[8*128];
  __shared__ float sb0[128];
  __shared__ bf16 h0s[128*128];   // swizzled; reused for h-tile later
  __shared__ bf16 sWT[128*128];   // swizzled W1^T
  const int t = threadIdx.x;
  const int w = t >> 6, lane = t & 63, l15 = lane & 15, g = lane >> 4;
  const int row_blk = blockIdx.x*128;
  for (int q = w; q < 32; q += 4)
    glds16((const char*)WTe + q*1024 + lane*16, (char*)(void*)sWT + q*1024);
  for (int i = t; i < 8*128; i += 256) sW0[i] = W0[i];
  if (t < 128) sb0[t] = b0[t];
  __syncthreads();
  // layer 1: thread owns 1 row, 64 cols
  {
    const int row = t & 127, colbase = (t >> 7) * 64;
    const float4* jp = (const float4*)(jets + ((size_t)row_blk + row)*8);
    float4 x0 = jp[0], x1 = jp[1];
    float x[8] = {x0.x,x0.y,x0.z,x0.w,x1.x,x1.y,x1.z,x1.w};
    const int sw = (row & 7) << 3;
#pragma unroll
    for (int cg = 0; cg < 16; ++cg) {
      int c0 = colbase + cg*4;
      bf16x4 o;
#pragma unroll
      for (int j = 0; j < 4; ++j) {
        float a = sb0[c0+j];
#pragma unroll
        for (int f = 0; f < 8; ++f) a = fmaf(x[f], sW0[f*128 + c0 + j], a);
        o[j] = (bf16)fmaxf(a, 0.f);
      }
      *(bf16x4*)(h0s + row*128 + (c0 ^ sw)) = o;
    }
  }
  __syncthreads();
  // layer 2: MFMA, 4 waves 2x2
  const int wr = (w & 1)*64, wc = (w >> 1)*64;
  f32x4 acc[4][4];
#pragma unroll
  for (int m = 0; m < 4; ++m)
#pragma unroll
    for (int n = 0; n < 4; ++n) acc[m][n] = (f32x4){0.f,0.f,0.f,0.f};
#pragma unroll
  for (int kk = 0; kk < 128; kk += 32) {
    bf16x8 bfr[4], wfr[4];
#pragma unroll
    for (int n = 0; n < 4; ++n) {
      int row = wr + n*16 + l15;
      bfr[n] = *(const bf16x8*)(h0s + row*128 + ((kk + 8*g) ^ ((row & 7) << 3)));
    }
#pragma unroll
    for (int m = 0; m < 4; ++m) {
      int c = wc + m*16 + l15;
      wfr[m] = *(const bf16x8*)(sWT + c*128 + ((kk + 8*g) ^ ((c & 7) << 3)));
    }
#pragma unroll
    for (int m = 0; m < 4; ++m)
#pragma unroll
      for (int n = 0; n < 4; ++n)
        acc[m][n] = __builtin_amdgcn_mfma_f32_16x16x32_bf16(wfr[m], bfr[n], acc[m][n], 0,0,0);
  }
  __syncthreads();   // everyone done reading h0s before overwrite
#pragma unroll
  for (int m = 0; m < 4; ++m) {
    f32x4 bs = *(const f32x4*)(b1 + wc + m*16 + g*4);
#pragma unroll
    for (int n = 0; n < 4; ++n) {
      int lr = wr + n*16 + l15;
      int r = row_blk + lr;
      int c0 = wc + m*16 + g*4;
      bf16x4 o;
#pragma unroll
      for (int j = 0; j < 4; ++j) o[j] = (bf16)fmaxf(acc[m][n][j] + bs[j], 0.f);
      *(bf16x4*)(h + (size_t)r*128 + c0) = o;
      *(bf16x4*)(h0s + lr*128 + (c0 ^ ((lr & 7) << 3))) = o;
    }
  }
  __syncthreads();
  // msg0: msgT = relu(htile @ Wm0 + bm0), TRANSOUT; Wm0 frags from global(L2)
  {
    f32x4 acc2[4][4];
#pragma unroll
    for (int m = 0; m < 4; ++m)
#pragma unroll
      for (int n = 0; n < 4; ++n) acc2[m][n] = (f32x4){0.f,0.f,0.f,0.f};
#pragma unroll
    for (int kk = 0; kk < 128; kk += 32) {
      bf16x8 bfr[4], wfr[4];
#pragma unroll
      for (int n = 0; n < 4; ++n) {
        int lr = wr + n*16 + l15;
        bfr[n] = *(const bf16x8*)(h0s + lr*128 + ((kk + 8*g) ^ ((lr & 7) << 3)));
      }
#pragma unroll
      for (int m = 0; m < 4; ++m) {
        int c = wc + m*16 + l15;
        wfr[m] = *(const bf16x8*)(WTm0 + c*128 + ((kk + 8*g) ^ ((c & 7) << 3)));
      }
#pragma unroll
      for (int m = 0; m < 4; ++m)
#pragma unroll
        for (int n = 0; n < 4; ++n)
          acc2[m][n] = __builtin_amdgcn_mfma_f32_16x16x32_bf16(bfr[n], wfr[m], acc2[m][n], 0,0,0);
    }
    const int b = row_blk >> 9;
    const int rbase = (row_blk & 511) + wr;
#pragma unroll
    for (int m = 0; m < 4; ++m) {
      int c = wc + m*16 + l15;
      float bc = bm0[c];
#pragma unroll
      for (int n = 0; n < 4; ++n) {
        int rl = rbase + n*16 + g*4;
        bf16x4 o;
#pragma unroll
        for (int j = 0; j < 4; ++j) o[j] = (bf16)fmaxf(acc2[m][n][j] + bc, 0.f);
        *(bf16x4*)(msgT + ((size_t)(b*128 + c))*512 + rl) = o;
      }
    }
  }
}

// -------------------------------------------------- fused per-iteration kernel
// 64-row / 128-thread / 32KB-LDS blocks, grid 1024 -> 5 blocks/CU (10 waves),
// with the SAME per-wave instruction mix as the proven 128-row version:
// Phase A: wave owns 32 rows (8 afr + 2 pfr per j-tile, 16 MFMA).
// Phase B: 64x64 wave tile (wave w -> cols w*64..+63), 4x4 frags.
// Phase C (DO_MSG): same geometry from htile.
// Dynamic LDS: DO_MSG ? 32KB (htile+aggs) : 16KB (aggs only).
template<bool DO_MSG>
__global__ __launch_bounds__(128) void iter_fused(
    const bf16* __restrict__ P, const float* __restrict__ rsum,
    const float* __restrict__ mask, const bf16* __restrict__ msgTin,
    bf16* __restrict__ h,
    const bf16* __restrict__ WTu, const float* __restrict__ bu,
    const bf16* __restrict__ WTm, const float* __restrict__ bm,
    bf16* __restrict__ msgTout) {
  extern __shared__ __align__(16) char smem[];
  bf16* htile = (bf16*)smem;                              // [64][128] 16KB (DO_MSG)
  bf16* aggs  = (bf16*)(smem + (DO_MSG ? 16384 : 0));     // [64][128] 16KB
  const int t = threadIdx.x;
  const int b  = blockIdx.x & 127;            // XCD-pinned batch
  const int ic = blockIdx.x >> 7;             // 0..7
  const int i0 = ic*64;
  const int w = t >> 6, lane = t & 63, l15 = lane & 15, g = lane >> 4;

  // ================= Phase A: agg rows i0 + w*32 .. +31 (pure GEMM)
  {
    const int i0w = i0 + w*32;
    float r_i[2];
#pragma unroll
    for (int r = 0; r < 2; ++r) r_i[r] = rsum[(size_t)b*Nn + i0w + r*16 + l15];
    f32x4 acc[2][8];
#pragma unroll
    for (int r = 0; r < 2; ++r)
#pragma unroll
      for (int m = 0; m < 8; ++m) acc[r][m] = (f32x4){0.f,0.f,0.f,0.f};
    const bf16* mB  = msgTin + (size_t)b*128*512 + (size_t)l15*512 + 8*g;
    const bf16* pB0 = P + ((size_t)(b*512) + i0w + l15)*512 + 8*g;
    const bf16* pB1 = pB0 + (size_t)16*512;
#pragma unroll 4
    for (int j0 = 0; j0 < Nn; j0 += 32) {
      bf16x8 afr[8];
#pragma unroll
      for (int m = 0; m < 8; ++m)
        afr[m] = *(const bf16x8*)(mB + m*8192 + j0);
      bf16x8 pfr[2];
      pfr[0] = *(const bf16x8*)(pB0 + j0);
      pfr[1] = *(const bf16x8*)(pB1 + j0);
#pragma unroll
      for (int m = 0; m < 8; ++m) {
        acc[0][m] = __builtin_amdgcn_mfma_f32_16x16x32_bf16(afr[m], pfr[0], acc[0][m], 0,0,0);
        acc[1][m] = __builtin_amdgcn_mfma_f32_16x16x32_bf16(afr[m], pfr[1], acc[1][m], 0,0,0);
      }
    }
    // epilogue -> aggs LDS (swizzled), normalized by r_i
#pragma unroll
    for (int r = 0; r < 2; ++r) {
      int lr = w*32 + r*16 + l15;      // local row 0..63
#pragma unroll
      for (int m = 0; m < 8; ++m) {
        bf16x4 o;
#pragma unroll
        for (int j = 0; j < 4; ++j) o[j] = (bf16)(acc[r][m][j] * r_i[r]);
        int c0 = m*16 + g*4;
        *(bf16x4*)(aggs + lr*128 + (c0 ^ ((lr & 7) << 3))) = o;
      }
    }
  }
  __syncthreads();   // aggs visible to both waves

  // ================= Phase B: h_new = relu([h|agg] @ Wu + bu) * mask
  const int wc = w*64;
  const size_t growbase = (size_t)b*Nn + i0;
  {
    f32x4 acc[4][4];
#pragma unroll
    for (int m = 0; m < 4; ++m)
#pragma unroll
      for (int n = 0; n < 4; ++n) acc[m][n] = (f32x4){0.f,0.f,0.f,0.f};
#pragma unroll
    for (int kk = 0; kk < 256; kk += 32) {
      bf16x8 bfr[4];
      if (kk < 128) {
#pragma unroll
        for (int n = 0; n < 4; ++n)
          bfr[n] = *(const bf16x8*)(h + (growbase + n*16 + l15)*128 + kk + 8*g);
      } else {
#pragma unroll
        for (int n = 0; n < 4; ++n) {
          int lr = n*16 + l15;
          int kl = (kk - 128) + 8*g;
          bfr[n] = *(const bf16x8*)(aggs + lr*128 + (kl ^ ((lr & 7) << 3)));
        }
      }
      bf16x8 wfr[4];
#pragma unroll
      for (int m = 0; m < 4; ++m) {
        int c = wc + m*16 + l15;
        wfr[m] = *(const bf16x8*)(WTu + c*256 + ((kk + 8*g) ^ ((c & 7) << 3)));
      }
#pragma unroll
      for (int m = 0; m < 4; ++m)
#pragma unroll
        for (int n = 0; n < 4; ++n)
          acc[m][n] = __builtin_amdgcn_mfma_f32_16x16x32_bf16(wfr[m], bfr[n], acc[m][n], 0,0,0);
    }
    __syncthreads();  // both waves' h reads (all 128 cols) drained before write
#pragma unroll
    for (int m = 0; m < 4; ++m) {
      f32x4 bs = *(const f32x4*)(bu + wc + m*16 + g*4);
#pragma unroll
      for (int n = 0; n < 4; ++n) {
        int lr = n*16 + l15;
        size_t r = growbase + lr;
        float mv = mask[r];
        bf16x4 o;
#pragma unroll
        for (int j = 0; j < 4; ++j)
          o[j] = (bf16)(fmaxf(acc[m][n][j] + bs[j], 0.f) * mv);
        int c0 = wc + m*16 + g*4;
        *(bf16x4*)(h + r*128 + c0) = o;
        if (DO_MSG)
          *(bf16x4*)(htile + lr*128 + (c0 ^ ((lr & 7) << 3))) = o;
      }
    }
  }
  if (!DO_MSG) return;
  __syncthreads();   // htile visible

  // ================= Phase C: msgTout = relu(h_new @ Wm + bm)^T
  {
    f32x4 acc[4][4];
#pragma unroll
    for (int m = 0; m < 4; ++m)
#pragma unroll
      for (int n = 0; n < 4; ++n) acc[m][n] = (f32x4){0.f,0.f,0.f,0.f};
#pragma unroll
    for (int kk = 0; kk < 128; kk += 32) {
      bf16x8 bfr[4], wfr[4];
#pragma unroll
      for (int n = 0; n < 4; ++n) {
        int lr = n*16 + l15;
        bfr[n] = *(const bf16x8*)(htile + lr*128 + ((kk + 8*g) ^ ((lr & 7) << 3)));
      }
#pragma unroll
      for (int m = 0; m < 4; ++m) {
        int c = wc + m*16 + l15;
        wfr[m] = *(const bf16x8*)(WTm + c*128 + ((kk + 8*g) ^ ((c & 7) << 3)));
      }
#pragma unroll
      for (int m = 0; m < 4; ++m)
#pragma unroll
        for (int n = 0; n < 4; ++n)
          acc[m][n] = __builtin_amdgcn_mfma_f32_16x16x32_bf16(bfr[n], wfr[m], acc[m][n], 0,0,0);
    }
#pragma unroll
    for (int m = 0; m < 4; ++m) {
      int c = wc + m*16 + l15;
      float bc = bm[c];
#pragma unroll
      for (int n = 0; n < 4; ++n) {
        int rl = i0 + n*16 + g*4;
        bf16x4 o;
#pragma unroll
        for (int j = 0; j < 4; ++j) o[j] = (bf16)fmaxf(acc[m][n][j] + bc, 0.f);
        *(bf16x4*)(msgTout + ((size_t)(b*128 + c))*512 + rl) = o;
      }
    }
  }
}

// -------------------------------------------------- fused pool + readout
__global__ __launch_bounds__(256) void pool_readout(
    const bf16* __restrict__ h, const float* __restrict__ mask,
    const float* __restrict__ W1, const float* __restrict__ b1,
    const float* __restrict__ W2, const float* __restrict__ b2,
    float* __restrict__ out) {
  __shared__ float part[3][128];
  __shared__ float pl[128];
  __shared__ float hid[128];
  int b = blockIdx.x, t = threadIdx.x, g = t >> 6, cp = (t & 63)*2;
  float a0 = 0.f, a1 = 0.f;
  for (int n = g*128; n < g*128+128; ++n) {
    float mv = mask[(size_t)b*Nn + n];
    bf16x2 v = *(const bf16x2*)(h + ((size_t)b*Nn + n)*128 + cp);
    a0 = fmaf((float)v[0], mv, a0);
    a1 = fmaf((float)v[1], mv, a1);
  }
  if (g > 0) { part[g-1][cp] = a0; part[g-1][cp+1] = a1; }
  __syncthreads();
  if (g == 0) {
    pl[cp]   = a0 + part[0][cp]   + part[1][cp]   + part[2][cp];
    pl[cp+1] = a1 + part[0][cp+1] + part[1][cp+1] + part[2][cp+1];
  }
  __syncthreads();
  if (t < 128) {
    float a = b1[t];
#pragma unroll 4
    for (int j = 0; j < 128; ++j) a = fmaf(pl[j], W1[j*128 + t], a);
    hid[t] = fmaxf(a, 0.f);
  }
  __syncthreads();
  if (t < 128) {
    float a = b2[t];
#pragma unroll 4
    for (int j = 0; j < 128; ++j) a = fmaf(hid[j], W2[j*128 + t], a);
    out[(size_t)b*128 + t] = a;
  }
}

// -------------------------------------------------- launch
extern "C" void kernel_launch(void* const* d_in, const int* in_sizes, int n_in,
                              void* d_out, int out_size, void* d_ws, size_t ws_size,
                              hipStream_t stream) {
  const float* jets = (const float*)d_in[0];
  const float* mask = (const float*)d_in[1];
  const float* eW0  = (const float*)d_in[2];
  const float* eb0  = (const float*)d_in[3];
  const float* eW1  = (const float*)d_in[4];
  const float* eb1  = (const float*)d_in[5];
  const float* Wm   = (const float*)d_in[6];
  const float* bm   = (const float*)d_in[7];
  const float* Wu   = (const float*)d_in[8];
  const float* bu   = (const float*)d_in[9];
  const float* rW1  = (const float*)d_in[10];
  const float* rb1  = (const float*)d_in[11];
  const float* rW2  = (const float*)d_in[12];
  const float* rb2  = (const float*)d_in[13];
  float* out = (float*)d_out;

  bf16* h     = (bf16*)d_ws;                    // ROWS*128
  bf16* msgTA = h     + (size_t)ROWS*128;       // ROWS*128 (layout [b][c][n])
  bf16* msgTB = msgTA + (size_t)ROWS*128;       // ROWS*128 (ping-pong)
  bf16* P     = msgTB + (size_t)ROWS*128;       // Bb*512*512 (67 MB, bf16 E)
  bf16* WTe   = P     + (size_t)Bb*512*512;     // 128*128
  bf16* WTm   = WTe   + 128*128;                // 3*128*128
  bf16* WTu   = WTm   + 3*128*128;              // 3*256*128
  float* rsum = (float*)(WTu + 3*256*128);      // ROWS (1/l_i)

  prep_all<<<640, 256, 0, stream>>>(eW1, Wm, Wu, WTe, WTm, WTu);
  pmat_kernel<<<Bb*4, 256, 0, stream>>>(jets, mask, P, rsum);
  embed_msg0<<<ROWS/128, 256, 0, stream>>>(jets, eW0, eb0, WTe, eb1,
                                           WTm, bm, h, msgTA);
  // iter 0: msgTA -> msgTB
  iter_fused<true><<<Bb*8, 128, 32768, stream>>>(
      P, rsum, mask, msgTA, h,
      WTu, bu, WTm + (size_t)1*128*128, bm + 1*128, msgTB);
  // iter 1: msgTB -> msgTA
  iter_fused<true><<<Bb*8, 128, 32768, stream>>>(
      P, rsum, mask, msgTB, h,
      WTu + (size_t)1*256*128, bu + 1*128,
      WTm + (size_t)2*128*128, bm + 2*128, msgTA);
  // iter 2 (no next msg): reads msgTA
  iter_fused<false><<<Bb*8, 128, 16384, stream>>>(
      P, rsum, mask, msgTA, h,
      WTu + (size_t)2*256*128, bu + 2*128, nullptr, nullptr, nullptr);

  pool_readout<<<Bb, 256, 0, stream>>>(h, mask, rW1, rb1, rW2, rb2, out);
}

// Round 15
// 189.528 us; speedup vs baseline: 1.2233x; 1.2185x over previous
//
#include <hip/hip_runtime.h>
#include <stdint.h>
#include <stddef.h>

#define Bb 128
#define Nn 512
#define Hh 128
#define ROWS (Bb*Nn)

typedef __bf16 bf16;
typedef __bf16 bf16x2 __attribute__((ext_vector_type(2)));
typedef __bf16 bf16x4 __attribute__((ext_vector_type(4)));
typedef __bf16 bf16x8 __attribute__((ext_vector_type(8)));
typedef float  f32x4  __attribute__((ext_vector_type(4)));

__device__ __forceinline__ void glds16(const void* g, void* l) {
  __builtin_amdgcn_global_load_lds(
      (const __attribute__((address_space(1))) void*)g,
      (__attribute__((address_space(3))) void*)l, 16, 0, 0);
}

// ============================ fragment-linear layouts ============================
// A 16(row)x32(k) bf16 MFMA subtile is stored as ONE 1KB block in lane order:
// lane l = g*16+l15 holds elements (row=l15, k=8g..8g+7) at block + l*16B.
// msgF[b]: block index kt*8 + mblk           (kt=j/32, mblk=channel/16)
// PF[b]:   block index it*16 + kt            (it=i/16,  kt=j/32)
// WuF[s]:  block index cblk*8 + kt (K=256)   WmF[s]: cblk*4 + kt (K=128)
// Consumers load block + lane*8 elements -> 64 lanes read contiguous 1KB.

// -------------------------------------------------- weight prep (all in one)
__global__ __launch_bounds__(256) void prep_all(
    const float* __restrict__ eW1, const float* __restrict__ Wm,
    const float* __restrict__ Wu, bf16* __restrict__ WTe,
    bf16* __restrict__ WmF, bf16* __restrict__ WuF) {
  int idx = blockIdx.x*256 + threadIdx.x;
  if (idx < 16384) {                       // eW1: 128x128 (old swizzled layout, LDS path)
    int k = idx >> 7, c = idx & 127;
    WTe[c*128 + (k ^ ((c & 7) << 3))] = (bf16)eW1[idx];
  } else if (idx < 65536) {                // Wm: 3x128x128 -> fragment-linear
    int sub = idx - 16384;
    int s = sub >> 14, r = sub & 16383;
    int k = r >> 7, c = r & 127;
    WmF[s*16384 + (((c>>4)*4 + (k>>5))*64 + ((k>>3)&3)*16 + (c&15))*8 + (k&7)] = (bf16)Wm[sub];
  } else if (idx < 65536 + 98304) {        // Wu: 3x256x128 -> fragment-linear
    int sub = idx - 65536;
    int s = sub >> 15, r = sub & 32767;
    int k = r >> 7, c = r & 127;
    WuF[s*32768 + (((c>>4)*8 + (k>>5))*64 + ((k>>3)&3)*16 + (c&15))*8 + (k&7)] = (bf16)Wu[sub];
  }
}

// -------------------------------------------------- P materialization (once)
// E_ij = exp(2 x_i.x_j - |x_j|^2 - pen_j - |x_i|^2), UNNORMALIZED, to PF
// (fragment-linear, coalesced 1KB writes); rsum = 1/sum_j E.
__global__ __launch_bounds__(256) void pmat_kernel(
    const float* __restrict__ jets, const float* __restrict__ mask,
    bf16* __restrict__ PF, float* __restrict__ rsum) {
  __shared__ float Xs[Nn*9];
  __shared__ float cbs[Nn];
  const int t = threadIdx.x;
  const int b = blockIdx.x & 127, ic = blockIdx.x >> 7;
  const int i0 = ic*128;
  const float* jb = jets + (size_t)b*Nn*8;
  for (int j = t; j < Nn; j += 256) {
    float s2 = 0.f;
#pragma unroll
    for (int f = 0; f < 8; ++f) { float v = jb[j*8+f]; Xs[j*9+f] = v; s2 = fmaf(v,v,s2); }
    cbs[j] = s2 + (mask[(size_t)b*Nn+j] > 0.f ? 0.f : 1e9f);
  }
  __syncthreads();
  const int w = t >> 6, lane = t & 63, l15 = lane & 15, g = lane >> 4;
  const int i0w = i0 + w*32;
  float xi2[2][8], sqi[2], lsum[2];
#pragma unroll
  for (int r = 0; r < 2; ++r) {
    int i = i0w + r*16 + l15;
    float sq = 0.f;
#pragma unroll
    for (int f = 0; f < 8; ++f) {
      float v = Xs[i*9+f];
      xi2[r][f] = 2.f*v;
      sq = fmaf(v, v, sq);
    }
    sqi[r] = sq;
    lsum[r] = 0.f;
  }
  // PF block base for it = i0w/16 + r; lane-linear offset
  bf16* Pr[2];
#pragma unroll
  for (int r = 0; r < 2; ++r) {
    int it = (i0w >> 4) + r;
    Pr[r] = PF + (((size_t)b*32 + it)*16)*512 + lane*8;
  }
#pragma unroll 2
  for (int j0 = 0; j0 < Nn; j0 += 32) {
    bf16x8 pfr[2];
#pragma unroll
    for (int e = 0; e < 8; ++e) {
      int j = j0 + 8*g + e;
      float xj[8];
#pragma unroll
      for (int f = 0; f < 8; ++f) xj[f] = Xs[j*9+f];
      float cb = cbs[j];
      float d0 = -(cb + sqi[0]);
      float d1 = -(cb + sqi[1]);
#pragma unroll
      for (int f = 0; f < 8; ++f) {
        d0 = fmaf(xi2[0][f], xj[f], d0);
        d1 = fmaf(xi2[1][f], xj[f], d1);
      }
      float ev0 = __expf(d0), ev1 = __expf(d1);
      lsum[0] += ev0; lsum[1] += ev1;
      pfr[0][e] = (bf16)ev0;
      pfr[1][e] = (bf16)ev1;
    }
#pragma unroll
    for (int r = 0; r < 2; ++r)
      *(bf16x8*)(Pr[r] + (j0 >> 5)*512) = pfr[r];
  }
#pragma unroll
  for (int r = 0; r < 2; ++r) {
    float s = lsum[r];
    s += __shfl_xor(s, 16, 64);
    s += __shfl_xor(s, 32, 64);
    if (g == 0) rsum[(size_t)b*Nn + i0w + r*16 + l15] = 1.f/s;
  }
}

// -------------------------------------------------- fused embed L1+L2+msg0
// h = relu(relu(jets@W0+b0)@W1+b1); msg0 -> msgF fragment-linear.
__global__ __launch_bounds__(256) void embed_msg0(
    const float* __restrict__ jets, const float* __restrict__ W0,
    const float* __restrict__ b0, const bf16* __restrict__ WTe,
    const float* __restrict__ b1, const bf16* __restrict__ WmF0,
    const float* __restrict__ bm0, bf16* __restrict__ h,
    bf16* __restrict__ msgF) {
  __shared__ float sW0[8*128];
  __shared__ float sb0[128];
  __shared__ bf16 h0s[128*128];   // swizzled; reused for h-tile later
  __shared__ bf16 sWT[128*128];   // swizzled W1^T
  const int t = threadIdx.x;
  const int w = t >> 6, lane = t & 63, l15 = lane & 15, g = lane >> 4;
  const int row_blk = blockIdx.x*128;
  for (int q = w; q < 32; q += 4)
    glds16((const char*)WTe + q*1024 + lane*16, (char*)(void*)sWT + q*1024);
  for (int i = t; i < 8*128; i += 256) sW0[i] = W0[i];
  if (t < 128) sb0[t] = b0[t];
  __syncthreads();
  // layer 1: thread owns 1 row, 64 cols
  {
    const int row = t & 127, colbase = (t >> 7) * 64;
    const float4* jp = (const float4*)(jets + ((size_t)row_blk + row)*8);
    float4 x0 = jp[0], x1 = jp[1];
    float x[8] = {x0.x,x0.y,x0.z,x0.w,x1.x,x1.y,x1.z,x1.w};
    const int sw = (row & 7) << 3;
#pragma unroll
    for (int cg = 0; cg < 16; ++cg) {
      int c0 = colbase + cg*4;
      bf16x4 o;
#pragma unroll
      for (int j = 0; j < 4; ++j) {
        float a = sb0[c0+j];
#pragma unroll
        for (int f = 0; f < 8; ++f) a = fmaf(x[f], sW0[f*128 + c0 + j], a);
        o[j] = (bf16)fmaxf(a, 0.f);
      }
      *(bf16x4*)(h0s + row*128 + (c0 ^ sw)) = o;
    }
  }
  __syncthreads();
  // layer 2: MFMA, 4 waves 2x2
  const int wr = (w & 1)*64, wc = (w >> 1)*64;
  f32x4 acc[4][4];
#pragma unroll
  for (int m = 0; m < 4; ++m)
#pragma unroll
    for (int n = 0; n < 4; ++n) acc[m][n] = (f32x4){0.f,0.f,0.f,0.f};
#pragma unroll
  for (int kk = 0; kk < 128; kk += 32) {
    bf16x8 bfr[4], wfr[4];
#pragma unroll
    for (int n = 0; n < 4; ++n) {
      int row = wr + n*16 + l15;
      bfr[n] = *(const bf16x8*)(h0s + row*128 + ((kk + 8*g) ^ ((row & 7) << 3)));
    }
#pragma unroll
    for (int m = 0; m < 4; ++m) {
      int c = wc + m*16 + l15;
      wfr[m] = *(const bf16x8*)(sWT + c*128 + ((kk + 8*g) ^ ((c & 7) << 3)));
    }
#pragma unroll
    for (int m = 0; m < 4; ++m)
#pragma unroll
      for (int n = 0; n < 4; ++n)
        acc[m][n] = __builtin_amdgcn_mfma_f32_16x16x32_bf16(wfr[m], bfr[n], acc[m][n], 0,0,0);
  }
  __syncthreads();   // everyone done reading h0s before overwrite
#pragma unroll
  for (int m = 0; m < 4; ++m) {
    f32x4 bs = *(const f32x4*)(b1 + wc + m*16 + g*4);
#pragma unroll
    for (int n = 0; n < 4; ++n) {
      int lr = wr + n*16 + l15;
      int r = row_blk + lr;
      int c0 = wc + m*16 + g*4;
      bf16x4 o;
#pragma unroll
      for (int j = 0; j < 4; ++j) o[j] = (bf16)fmaxf(acc[m][n][j] + bs[j], 0.f);
      *(bf16x4*)(h + (size_t)r*128 + c0) = o;
      *(bf16x4*)(h0s + lr*128 + (c0 ^ ((lr & 7) << 3))) = o;
    }
  }
  __syncthreads();
  // msg0: relu(htile @ Wm0 + bm0) -> msgF fragment-linear blocks
  {
    f32x4 acc2[4][4];
#pragma unroll
    for (int m = 0; m < 4; ++m)
#pragma unroll
      for (int n = 0; n < 4; ++n) acc2[m][n] = (f32x4){0.f,0.f,0.f,0.f};
#pragma unroll
    for (int kk = 0; kk < 128; kk += 32) {
      bf16x8 bfr[4], wfr[4];
#pragma unroll
      for (int n = 0; n < 4; ++n) {
        int lr = wr + n*16 + l15;
        bfr[n] = *(const bf16x8*)(h0s + lr*128 + ((kk + 8*g) ^ ((lr & 7) << 3)));
      }
#pragma unroll
      for (int m = 0; m < 4; ++m) {
        int cblk = (wc >> 4) + m;
        wfr[m] = *(const bf16x8*)(WmF0 + (size_t)(cblk*4 + (kk >> 5))*512 + lane*8);
      }
#pragma unroll
      for (int m = 0; m < 4; ++m)
#pragma unroll
        for (int n = 0; n < 4; ++n)
          acc2[m][n] = __builtin_amdgcn_mfma_f32_16x16x32_bf16(bfr[n], wfr[m], acc2[m][n], 0,0,0);
    }
    const int b = row_blk >> 9;
    const int rbase = (row_blk & 511) + wr;
#pragma unroll
    for (int m = 0; m < 4; ++m) {
      int c = wc + m*16 + l15;
      int mblk = (wc >> 4) + m;
      float bc = bm0[c];
#pragma unroll
      for (int n = 0; n < 4; ++n) {
        int rl = rbase + n*16 + g*4;
        bf16x4 o;
#pragma unroll
        for (int j = 0; j < 4; ++j) o[j] = (bf16)fmaxf(acc2[m][n][j] + bc, 0.f);
        size_t off = (size_t)b*65536 + (size_t)((rl>>5)*8 + mblk)*512
                   + (((rl>>3)&3)*16 + l15)*8 + (rl&7);
        *(bf16x4*)(msgF + off) = o;
      }
    }
  }
}

// -------------------------------------------------- fused per-iteration kernel
// Phase A: pure GEMM on fragment-linear PF/msgF (all loads coalesced 1KB).
// Phase B: h_new = relu([h|agg]@Wu+bu)*mask (in-place h); WuF coalesced.
// Phase C (DO_MSG): msgFout = relu(h_new@Wm+bm)^T (fragment-linear out).
// msgFin != msgFout (ping-pong). Block = (b = wgid&127 [XCD], ic = wgid>>7).
template<bool DO_MSG>
__global__ __launch_bounds__(256) void iter_fused(
    const bf16* __restrict__ PF, const float* __restrict__ rsum,
    const float* __restrict__ mask, const bf16* __restrict__ msgFin,
    bf16* __restrict__ h,
    const bf16* __restrict__ WuF, const float* __restrict__ bu,
    const bf16* __restrict__ WmF, const float* __restrict__ bm,
    bf16* __restrict__ msgFout) {
  __shared__ __align__(16) char smem[65536];
  bf16* htile = (bf16*)smem;                 // [128][128] 32KB
  bf16* aggs  = (bf16*)(smem + 32768);       // [128][128] 32KB
  const int t = threadIdx.x;
  const int b  = blockIdx.x & 127;
  const int ic = blockIdx.x >> 7;             // 0..3
  const int i0 = ic*128;
  const int w = t >> 6, lane = t & 63, l15 = lane & 15, g = lane >> 4;

  // ================= Phase A: agg rows i0 + w*32 .. +31 (coalesced pure GEMM)
  {
    const int i0w = i0 + w*32;
    float r_i[2];
#pragma unroll
    for (int r = 0; r < 2; ++r) r_i[r] = rsum[(size_t)b*Nn + i0w + r*16 + l15];
    f32x4 acc[2][8];
#pragma unroll
    for (int r = 0; r < 2; ++r)
#pragma unroll
      for (int m = 0; m < 8; ++m) acc[r][m] = (f32x4){0.f,0.f,0.f,0.f};
    const bf16* mBF = msgFin + (size_t)b*65536 + lane*8;
    const bf16* pBF = PF + ((size_t)b*32 + (i0w >> 4))*16*512 + lane*8;
#pragma unroll 4
    for (int kt = 0; kt < 16; ++kt) {
      bf16x8 afr[8];
#pragma unroll
      for (int m = 0; m < 8; ++m)
        afr[m] = *(const bf16x8*)(mBF + (kt*8 + m)*512);
      bf16x8 pfr[2];
      pfr[0] = *(const bf16x8*)(pBF + kt*512);
      pfr[1] = *(const bf16x8*)(pBF + (16 + kt)*512);
#pragma unroll
      for (int m = 0; m < 8; ++m) {
        acc[0][m] = __builtin_amdgcn_mfma_f32_16x16x32_bf16(afr[m], pfr[0], acc[0][m], 0,0,0);
        acc[1][m] = __builtin_amdgcn_mfma_f32_16x16x32_bf16(afr[m], pfr[1], acc[1][m], 0,0,0);
      }
    }
    // epilogue -> aggs LDS (swizzled), normalized by r_i
#pragma unroll
    for (int r = 0; r < 2; ++r) {
      int lr = w*32 + r*16 + l15;      // local row 0..127
#pragma unroll
      for (int m = 0; m < 8; ++m) {
        bf16x4 o;
#pragma unroll
        for (int j = 0; j < 4; ++j) o[j] = (bf16)(acc[r][m][j] * r_i[r]);
        int c0 = m*16 + g*4;
        *(bf16x4*)(aggs + lr*128 + (c0 ^ ((lr & 7) << 3))) = o;
      }
    }
  }
  __syncthreads();   // aggs visible to all waves

  // ================= Phase B: h_new = relu([h|agg] @ Wu + bu) * mask
  const int wr = (w & 1)*64, wc = (w >> 1)*64;
  const size_t growbase = (size_t)b*Nn + i0;
  {
    f32x4 acc[4][4];
#pragma unroll
    for (int m = 0; m < 4; ++m)
#pragma unroll
      for (int n = 0; n < 4; ++n) acc[m][n] = (f32x4){0.f,0.f,0.f,0.f};
#pragma unroll
    for (int kk = 0; kk < 256; kk += 32) {
      bf16x8 bfr[4];
      if (kk < 128) {
#pragma unroll
        for (int n = 0; n < 4; ++n)
          bfr[n] = *(const bf16x8*)(h + (growbase + wr + n*16 + l15)*128 + kk + 8*g);
      } else {
#pragma unroll
        for (int n = 0; n < 4; ++n) {
          int lr = wr + n*16 + l15;
          int kl = (kk - 128) + 8*g;
          bfr[n] = *(const bf16x8*)(aggs + lr*128 + (kl ^ ((lr & 7) << 3)));
        }
      }
      bf16x8 wfr[4];
#pragma unroll
      for (int m = 0; m < 4; ++m) {
        int cblk = (wc >> 4) + m;
        wfr[m] = *(const bf16x8*)(WuF + (size_t)(cblk*8 + (kk >> 5))*512 + lane*8);
      }
#pragma unroll
      for (int m = 0; m < 4; ++m)
#pragma unroll
        for (int n = 0; n < 4; ++n)
          acc[m][n] = __builtin_amdgcn_mfma_f32_16x16x32_bf16(wfr[m], bfr[n], acc[m][n], 0,0,0);
    }
    __syncthreads();  // all h reads (cross-wave cols) + aggs reads drained
#pragma unroll
    for (int m = 0; m < 4; ++m) {
      f32x4 bs = *(const f32x4*)(bu + wc + m*16 + g*4);
#pragma unroll
      for (int n = 0; n < 4; ++n) {
        int lr = wr + n*16 + l15;
        size_t r = growbase + lr;
        float mv = mask[r];
        bf16x4 o;
#pragma unroll
        for (int j = 0; j < 4; ++j)
          o[j] = (bf16)(fmaxf(acc[m][n][j] + bs[j], 0.f) * mv);
        int c0 = wc + m*16 + g*4;
        *(bf16x4*)(h + r*128 + c0) = o;
        if (DO_MSG)
          *(bf16x4*)(htile + lr*128 + (c0 ^ ((lr & 7) << 3))) = o;
      }
    }
  }
  if (!DO_MSG) return;
  __syncthreads();   // htile visible

  // ================= Phase C: msgFout = relu(h_new @ Wm + bm)^T (frag-linear)
  {
    f32x4 acc[4][4];
#pragma unroll
    for (int m = 0; m < 4; ++m)
#pragma unroll
      for (int n = 0; n < 4; ++n) acc[m][n] = (f32x4){0.f,0.f,0.f,0.f};
#pragma unroll
    for (int kk = 0; kk < 128; kk += 32) {
      bf16x8 bfr[4], wfr[4];
#pragma unroll
      for (int n = 0; n < 4; ++n) {
        int lr = wr + n*16 + l15;
        bfr[n] = *(const bf16x8*)(htile + lr*128 + ((kk + 8*g) ^ ((lr & 7) << 3)));
      }
#pragma unroll
      for (int m = 0; m < 4; ++m) {
        int cblk = (wc >> 4) + m;
        wfr[m] = *(const bf16x8*)(WmF + (size_t)(cblk*4 + (kk >> 5))*512 + lane*8);
      }
#pragma unroll
      for (int m = 0; m < 4; ++m)
#pragma unroll
        for (int n = 0; n < 4; ++n)
          acc[m][n] = __builtin_amdgcn_mfma_f32_16x16x32_bf16(bfr[n], wfr[m], acc[m][n], 0,0,0);
    }
#pragma unroll
    for (int m = 0; m < 4; ++m) {
      int c = wc + m*16 + l15;
      int mblk = (wc >> 4) + m;
      float bc = bm[c];
#pragma unroll
      for (int n = 0; n < 4; ++n) {
        int rl = i0 + wr + n*16 + g*4;
        bf16x4 o;
#pragma unroll
        for (int j = 0; j < 4; ++j) o[j] = (bf16)fmaxf(acc[m][n][j] + bc, 0.f);
        size_t off = (size_t)b*65536 + (size_t)((rl>>5)*8 + mblk)*512
                   + (((rl>>3)&3)*16 + l15)*8 + (rl&7);
        *(bf16x4*)(msgFout + off) = o;
      }
    }
  }
}

// -------------------------------------------------- fused pool + readout
__global__ __launch_bounds__(256) void pool_readout(
    const bf16* __restrict__ h, const float* __restrict__ mask,
    const float* __restrict__ W1, const float* __restrict__ b1,
    const float* __restrict__ W2, const float* __restrict__ b2,
    float* __restrict__ out) {
  __shared__ float part[3][128];
  __shared__ float pl[128];
  __shared__ float hid[128];
  int b = blockIdx.x, t = threadIdx.x, g = t >> 6, cp = (t & 63)*2;
  float a0 = 0.f, a1 = 0.f;
  for (int n = g*128; n < g*128+128; ++n) {
    float mv = mask[(size_t)b*Nn + n];
    bf16x2 v = *(const bf16x2*)(h + ((size_t)b*Nn + n)*128 + cp);
    a0 = fmaf((float)v[0], mv, a0);
    a1 = fmaf((float)v[1], mv, a1);
  }
  if (g > 0) { part[g-1][cp] = a0; part[g-1][cp+1] = a1; }
  __syncthreads();
  if (g == 0) {
    pl[cp]   = a0 + part[0][cp]   + part[1][cp]   + part[2][cp];
    pl[cp+1] = a1 + part[0][cp+1] + part[1][cp+1] + part[2][cp+1];
  }
  __syncthreads();
  if (t < 128) {
    float a = b1[t];
#pragma unroll 4
    for (int j = 0; j < 128; ++j) a = fmaf(pl[j], W1[j*128 + t], a);
    hid[t] = fmaxf(a, 0.f);
  }
  __syncthreads();
  if (t < 128) {
    float a = b2[t];
#pragma unroll 4
    for (int j = 0; j < 128; ++j) a = fmaf(hid[j], W2[j*128 + t], a);
    out[(size_t)b*128 + t] = a;
  }
}

// -------------------------------------------------- launch
extern "C" void kernel_launch(void* const* d_in, const int* in_sizes, int n_in,
                              void* d_out, int out_size, void* d_ws, size_t ws_size,
                              hipStream_t stream) {
  const float* jets = (const float*)d_in[0];
  const float* mask = (const float*)d_in[1];
  const float* eW0  = (const float*)d_in[2];
  const float* eb0  = (const float*)d_in[3];
  const float* eW1  = (const float*)d_in[4];
  const float* eb1  = (const float*)d_in[5];
  const float* Wm   = (const float*)d_in[6];
  const float* bm   = (const float*)d_in[7];
  const float* Wu   = (const float*)d_in[8];
  const float* bu   = (const float*)d_in[9];
  const float* rW1  = (const float*)d_in[10];
  const float* rb1  = (const float*)d_in[11];
  const float* rW2  = (const float*)d_in[12];
  const float* rb2  = (const float*)d_in[13];
  float* out = (float*)d_out;

  bf16* h     = (bf16*)d_ws;                    // ROWS*128
  bf16* msgFA = h     + (size_t)ROWS*128;       // ROWS*128 (fragment-linear)
  bf16* msgFB = msgFA + (size_t)ROWS*128;       // ROWS*128 (ping-pong)
  bf16* PF    = msgFB + (size_t)ROWS*128;       // Bb*512*512 (67 MB, frag-linear E)
  bf16* WTe   = PF    + (size_t)Bb*512*512;     // 128*128 (old layout)
  bf16* WmF   = WTe   + 128*128;                // 3*128*128 (frag-linear)
  bf16* WuF   = WmF   + 3*128*128;              // 3*256*128 (frag-linear)
  float* rsum = (float*)(WuF + 3*256*128);      // ROWS (1/l_i)

  prep_all<<<640, 256, 0, stream>>>(eW1, Wm, Wu, WTe, WmF, WuF);
  pmat_kernel<<<Bb*4, 256, 0, stream>>>(jets, mask, PF, rsum);
  embed_msg0<<<ROWS/128, 256, 0, stream>>>(jets, eW0, eb0, WTe, eb1,
                                           WmF, bm, h, msgFA);
  // iter 0: msgFA -> msgFB
  iter_fused<true><<<Bb*4, 256, 0, stream>>>(
      PF, rsum, mask, msgFA, h,
      WuF, bu, WmF + (size_t)1*128*128, bm + 1*128, msgFB);
  // iter 1: msgFB -> msgFA
  iter_fused<true><<<Bb*4, 256, 0, stream>>>(
      PF, rsum, mask, msgFB, h,
      WuF + (size_t)1*256*128, bu + 1*128,
      WmF + (size_t)2*128*128, bm + 2*128, msgFA);
  // iter 2 (no next msg): reads msgFA
  iter_fused<false><<<Bb*4, 256, 0, stream>>>(
      PF, rsum, mask, msgFA, h,
      WuF + (size_t)2*256*128, bu + 2*128, nullptr, nullptr, nullptr);

  pool_readout<<<Bb, 256, 0, stream>>>(h, mask, rW1, rb1, rW2, rb2, out);
}

// Round 16
// 158.533 us; speedup vs baseline: 1.4625x; 1.1955x over previous
//
#include <hip/hip_runtime.h>
#include <stdint.h>
#include <stddef.h>

#define Bb 128
#define Nn 512
#define Hh 128
#define ROWS (Bb*Nn)

typedef __bf16 bf16;
typedef __bf16 bf16x2 __attribute__((ext_vector_type(2)));
typedef __bf16 bf16x4 __attribute__((ext_vector_type(4)));
typedef __bf16 bf16x8 __attribute__((ext_vector_type(8)));
typedef float  f32x4  __attribute__((ext_vector_type(4)));

__device__ __forceinline__ void glds16(const void* g, void* l) {
  __builtin_amdgcn_global_load_lds(
      (const __attribute__((address_space(1))) void*)g,
      (__attribute__((address_space(3))) void*)l, 16, 0, 0);
}

// ============================ fragment-linear layouts ============================
// A 16(row)x32(k) bf16 MFMA subtile is stored as ONE 1KB block in lane order:
// lane l = g*16+l15 holds elements (row=l15, k=8g..8g+7) at block + l*16B.
// msgF[b]: block index kt*8 + mblk           (kt=j/32, mblk=channel/16)
// PF[b]:   block index it*16 + kt            (it=i/16,  kt=j/32)
// WuF[s]:  block index cblk*8 + kt (K=256)   WmF[s]: cblk*4 + kt (K=128)
// Consumers load block + lane*8 elements -> 64 lanes read contiguous 1KB.

// -------------------------------------------------- weight prep (all in one)
__global__ __launch_bounds__(256) void prep_all(
    const float* __restrict__ eW1, const float* __restrict__ Wm,
    const float* __restrict__ Wu, bf16* __restrict__ WTe,
    bf16* __restrict__ WmF, bf16* __restrict__ WuF) {
  int idx = blockIdx.x*256 + threadIdx.x;
  if (idx < 16384) {                       // eW1: 128x128 (old swizzled layout, LDS path)
    int k = idx >> 7, c = idx & 127;
    WTe[c*128 + (k ^ ((c & 7) << 3))] = (bf16)eW1[idx];
  } else if (idx < 65536) {                // Wm: 3x128x128 -> fragment-linear
    int sub = idx - 16384;
    int s = sub >> 14, r = sub & 16383;
    int k = r >> 7, c = r & 127;
    WmF[s*16384 + (((c>>4)*4 + (k>>5))*64 + ((k>>3)&3)*16 + (c&15))*8 + (k&7)] = (bf16)Wm[sub];
  } else if (idx < 65536 + 98304) {        // Wu: 3x256x128 -> fragment-linear
    int sub = idx - 65536;
    int s = sub >> 15, r = sub & 32767;
    int k = r >> 7, c = r & 127;
    WuF[s*32768 + (((c>>4)*8 + (k>>5))*64 + ((k>>3)&3)*16 + (c&15))*8 + (k&7)] = (bf16)Wu[sub];
  }
}

// -------------------------------------------------- P materialization (once)
// E_ij = exp(2 x_i.x_j - |x_j|^2 - pen_j - |x_i|^2), UNNORMALIZED, to PF
// (fragment-linear, coalesced 1KB writes); rsum = 1/sum_j E.
__global__ __launch_bounds__(256) void pmat_kernel(
    const float* __restrict__ jets, const float* __restrict__ mask,
    bf16* __restrict__ PF, float* __restrict__ rsum) {
  __shared__ float Xs[Nn*9];
  __shared__ float cbs[Nn];
  const int t = threadIdx.x;
  const int b = blockIdx.x & 127, ic = blockIdx.x >> 7;
  const int i0 = ic*128;
  const float* jb = jets + (size_t)b*Nn*8;
  for (int j = t; j < Nn; j += 256) {
    float s2 = 0.f;
#pragma unroll
    for (int f = 0; f < 8; ++f) { float v = jb[j*8+f]; Xs[j*9+f] = v; s2 = fmaf(v,v,s2); }
    cbs[j] = s2 + (mask[(size_t)b*Nn+j] > 0.f ? 0.f : 1e9f);
  }
  __syncthreads();
  const int w = t >> 6, lane = t & 63, l15 = lane & 15, g = lane >> 4;
  const int i0w = i0 + w*32;
  float xi2[2][8], sqi[2], lsum[2];
#pragma unroll
  for (int r = 0; r < 2; ++r) {
    int i = i0w + r*16 + l15;
    float sq = 0.f;
#pragma unroll
    for (int f = 0; f < 8; ++f) {
      float v = Xs[i*9+f];
      xi2[r][f] = 2.f*v;
      sq = fmaf(v, v, sq);
    }
    sqi[r] = sq;
    lsum[r] = 0.f;
  }
  bf16* Pr[2];
#pragma unroll
  for (int r = 0; r < 2; ++r) {
    int it = (i0w >> 4) + r;
    Pr[r] = PF + (((size_t)b*32 + it)*16)*512 + lane*8;
  }
#pragma unroll 2
  for (int j0 = 0; j0 < Nn; j0 += 32) {
    bf16x8 pfr[2];
#pragma unroll
    for (int e = 0; e < 8; ++e) {
      int j = j0 + 8*g + e;
      float xj[8];
#pragma unroll
      for (int f = 0; f < 8; ++f) xj[f] = Xs[j*9+f];
      float cb = cbs[j];
      float d0 = -(cb + sqi[0]);
      float d1 = -(cb + sqi[1]);
#pragma unroll
      for (int f = 0; f < 8; ++f) {
        d0 = fmaf(xi2[0][f], xj[f], d0);
        d1 = fmaf(xi2[1][f], xj[f], d1);
      }
      float ev0 = __expf(d0), ev1 = __expf(d1);
      lsum[0] += ev0; lsum[1] += ev1;
      pfr[0][e] = (bf16)ev0;
      pfr[1][e] = (bf16)ev1;
    }
#pragma unroll
    for (int r = 0; r < 2; ++r)
      *(bf16x8*)(Pr[r] + (j0 >> 5)*512) = pfr[r];
  }
#pragma unroll
  for (int r = 0; r < 2; ++r) {
    float s = lsum[r];
    s += __shfl_xor(s, 16, 64);
    s += __shfl_xor(s, 32, 64);
    if (g == 0) rsum[(size_t)b*Nn + i0w + r*16 + l15] = 1.f/s;
  }
}

// -------------------------------------------------- fused embed L1+L2+msg0
// h = relu(relu(jets@W0+b0)@W1+b1); msg0 -> msgF fragment-linear.
__global__ __launch_bounds__(256) void embed_msg0(
    const float* __restrict__ jets, const float* __restrict__ W0,
    const float* __restrict__ b0, const bf16* __restrict__ WTe,
    const float* __restrict__ b1, const bf16* __restrict__ WmF0,
    const float* __restrict__ bm0, bf16* __restrict__ h,
    bf16* __restrict__ msgF) {
  __shared__ float sW0[8*128];
  __shared__ float sb0[128];
  __shared__ bf16 h0s[128*128];   // swizzled; reused for h-tile later
  __shared__ bf16 sWT[128*128];   // swizzled W1^T
  const int t = threadIdx.x;
  const int w = t >> 6, lane = t & 63, l15 = lane & 15, g = lane >> 4;
  const int row_blk = blockIdx.x*128;
  for (int q = w; q < 32; q += 4)
    glds16((const char*)WTe + q*1024 + lane*16, (char*)(void*)sWT + q*1024);
  for (int i = t; i < 8*128; i += 256) sW0[i] = W0[i];
  if (t < 128) sb0[t] = b0[t];
  __syncthreads();
  // layer 1: thread owns 1 row, 64 cols
  {
    const int row = t & 127, colbase = (t >> 7) * 64;
    const float4* jp = (const float4*)(jets + ((size_t)row_blk + row)*8);
    float4 x0 = jp[0], x1 = jp[1];
    float x[8] = {x0.x,x0.y,x0.z,x0.w,x1.x,x1.y,x1.z,x1.w};
    const int sw = (row & 7) << 3;
#pragma unroll
    for (int cg = 0; cg < 16; ++cg) {
      int c0 = colbase + cg*4;
      bf16x4 o;
#pragma unroll
      for (int j = 0; j < 4; ++j) {
        float a = sb0[c0+j];
#pragma unroll
        for (int f = 0; f < 8; ++f) a = fmaf(x[f], sW0[f*128 + c0 + j], a);
        o[j] = (bf16)fmaxf(a, 0.f);
      }
      *(bf16x4*)(h0s + row*128 + (c0 ^ sw)) = o;
    }
  }
  __syncthreads();
  // layer 2: MFMA, 4 waves 2x2
  const int wr = (w & 1)*64, wc = (w >> 1)*64;
  f32x4 acc[4][4];
#pragma unroll
  for (int m = 0; m < 4; ++m)
#pragma unroll
    for (int n = 0; n < 4; ++n) acc[m][n] = (f32x4){0.f,0.f,0.f,0.f};
#pragma unroll
  for (int kk = 0; kk < 128; kk += 32) {
    bf16x8 bfr[4], wfr[4];
#pragma unroll
    for (int n = 0; n < 4; ++n) {
      int row = wr + n*16 + l15;
      bfr[n] = *(const bf16x8*)(h0s + row*128 + ((kk + 8*g) ^ ((row & 7) << 3)));
    }
#pragma unroll
    for (int m = 0; m < 4; ++m) {
      int c = wc + m*16 + l15;
      wfr[m] = *(const bf16x8*)(sWT + c*128 + ((kk + 8*g) ^ ((c & 7) << 3)));
    }
#pragma unroll
    for (int m = 0; m < 4; ++m)
#pragma unroll
      for (int n = 0; n < 4; ++n)
        acc[m][n] = __builtin_amdgcn_mfma_f32_16x16x32_bf16(wfr[m], bfr[n], acc[m][n], 0,0,0);
  }
  __syncthreads();   // everyone done reading h0s before overwrite
#pragma unroll
  for (int m = 0; m < 4; ++m) {
    f32x4 bs = *(const f32x4*)(b1 + wc + m*16 + g*4);
#pragma unroll
    for (int n = 0; n < 4; ++n) {
      int lr = wr + n*16 + l15;
      int r = row_blk + lr;
      int c0 = wc + m*16 + g*4;
      bf16x4 o;
#pragma unroll
      for (int j = 0; j < 4; ++j) o[j] = (bf16)fmaxf(acc[m][n][j] + bs[j], 0.f);
      *(bf16x4*)(h + (size_t)r*128 + c0) = o;
      *(bf16x4*)(h0s + lr*128 + (c0 ^ ((lr & 7) << 3))) = o;
    }
  }
  __syncthreads();
  // msg0: relu(htile @ Wm0 + bm0) -> msgF fragment-linear blocks
  {
    f32x4 acc2[4][4];
#pragma unroll
    for (int m = 0; m < 4; ++m)
#pragma unroll
      for (int n = 0; n < 4; ++n) acc2[m][n] = (f32x4){0.f,0.f,0.f,0.f};
#pragma unroll
    for (int kk = 0; kk < 128; kk += 32) {
      bf16x8 bfr[4], wfr[4];
#pragma unroll
      for (int n = 0; n < 4; ++n) {
        int lr = wr + n*16 + l15;
        bfr[n] = *(const bf16x8*)(h0s + lr*128 + ((kk + 8*g) ^ ((lr & 7) << 3)));
      }
#pragma unroll
      for (int m = 0; m < 4; ++m) {
        int cblk = (wc >> 4) + m;
        wfr[m] = *(const bf16x8*)(WmF0 + (size_t)(cblk*4 + (kk >> 5))*512 + lane*8);
      }
#pragma unroll
      for (int m = 0; m < 4; ++m)
#pragma unroll
        for (int n = 0; n < 4; ++n)
          acc2[m][n] = __builtin_amdgcn_mfma_f32_16x16x32_bf16(bfr[n], wfr[m], acc2[m][n], 0,0,0);
    }
    const int b = row_blk >> 9;
    const int rbase = (row_blk & 511) + wr;
#pragma unroll
    for (int m = 0; m < 4; ++m) {
      int c = wc + m*16 + l15;
      int mblk = (wc >> 4) + m;
      float bc = bm0[c];
#pragma unroll
      for (int n = 0; n < 4; ++n) {
        int rl = rbase + n*16 + g*4;
        bf16x4 o;
#pragma unroll
        for (int j = 0; j < 4; ++j) o[j] = (bf16)fmaxf(acc2[m][n][j] + bc, 0.f);
        size_t off = (size_t)b*65536 + (size_t)((rl>>5)*8 + mblk)*512
                   + (((rl>>3)&3)*16 + l15)*8 + (rl&7);
        *(bf16x4*)(msgF + off) = o;
      }
    }
  }
}

// -------------------------------------------------- fused per-iteration kernel
// Phase A: pure GEMM on fragment-linear PF/msgF, EXPLICIT 2-deep double-buffer
// of the 10-load cluster. __launch_bounds__(256,1) releases the VGPR budget
// (LDS binds occupancy at 2 blocks/CU; VGPR up to 256/wave is free) so the
// prefetch buffers actually materialize (R13's attempt folded at 104 VGPR).
// Phase B: h_new = relu([h|agg]@Wu+bu)*mask (in-place h); WuF coalesced.
// Phase C (DO_MSG): msgFout = relu(h_new@Wm+bm)^T (fragment-linear out).
template<bool DO_MSG>
__global__ __launch_bounds__(256, 1) void iter_fused(
    const bf16* __restrict__ PF, const float* __restrict__ rsum,
    const float* __restrict__ mask, const bf16* __restrict__ msgFin,
    bf16* __restrict__ h,
    const bf16* __restrict__ WuF, const float* __restrict__ bu,
    const bf16* __restrict__ WmF, const float* __restrict__ bm,
    bf16* __restrict__ msgFout) {
  __shared__ __align__(16) char smem[65536];
  bf16* htile = (bf16*)smem;                 // [128][128] 32KB
  bf16* aggs  = (bf16*)(smem + 32768);       // [128][128] 32KB
  const int t = threadIdx.x;
  const int b  = blockIdx.x & 127;
  const int ic = blockIdx.x >> 7;             // 0..3
  const int i0 = ic*128;
  const int w = t >> 6, lane = t & 63, l15 = lane & 15, g = lane >> 4;

  // ================= Phase A: agg rows i0 + w*32 .. +31 (pipelined pure GEMM)
  {
    const int i0w = i0 + w*32;
    float r_i[2];
#pragma unroll
    for (int r = 0; r < 2; ++r) r_i[r] = rsum[(size_t)b*Nn + i0w + r*16 + l15];
    f32x4 acc[2][8];
#pragma unroll
    for (int r = 0; r < 2; ++r)
#pragma unroll
      for (int m = 0; m < 8; ++m) acc[r][m] = (f32x4){0.f,0.f,0.f,0.f};
    const bf16* mBF = msgFin + (size_t)b*65536 + lane*8;
    const bf16* pBF = PF + ((size_t)b*32 + (i0w >> 4))*16*512 + lane*8;

    bf16x8 afrA[8], afrB[8], pfrA[2], pfrB[2];
    auto loadA = [&](int kt) {
#pragma unroll
      for (int m = 0; m < 8; ++m) afrA[m] = *(const bf16x8*)(mBF + (kt*8 + m)*512);
      pfrA[0] = *(const bf16x8*)(pBF + kt*512);
      pfrA[1] = *(const bf16x8*)(pBF + (16 + kt)*512);
    };
    auto loadB = [&](int kt) {
#pragma unroll
      for (int m = 0; m < 8; ++m) afrB[m] = *(const bf16x8*)(mBF + (kt*8 + m)*512);
      pfrB[0] = *(const bf16x8*)(pBF + kt*512);
      pfrB[1] = *(const bf16x8*)(pBF + (16 + kt)*512);
    };
    auto compute = [&](const bf16x8* afr, const bf16x8* pfr) {
#pragma unroll
      for (int m = 0; m < 8; ++m) {
        acc[0][m] = __builtin_amdgcn_mfma_f32_16x16x32_bf16(afr[m], pfr[0], acc[0][m], 0,0,0);
        acc[1][m] = __builtin_amdgcn_mfma_f32_16x16x32_bf16(afr[m], pfr[1], acc[1][m], 0,0,0);
      }
    };

    loadA(0);
#pragma unroll
    for (int kt = 0; kt < 16; kt += 2) {
      loadB(kt + 1);
      compute(afrA, pfrA);
      if (kt + 2 < 16) loadA(kt + 2);
      compute(afrB, pfrB);
    }
    // epilogue -> aggs LDS (swizzled), normalized by r_i
#pragma unroll
    for (int r = 0; r < 2; ++r) {
      int lr = w*32 + r*16 + l15;      // local row 0..127
#pragma unroll
      for (int m = 0; m < 8; ++m) {
        bf16x4 o;
#pragma unroll
        for (int j = 0; j < 4; ++j) o[j] = (bf16)(acc[r][m][j] * r_i[r]);
        int c0 = m*16 + g*4;
        *(bf16x4*)(aggs + lr*128 + (c0 ^ ((lr & 7) << 3))) = o;
      }
    }
  }
  __syncthreads();   // aggs visible to all waves

  // ================= Phase B: h_new = relu([h|agg] @ Wu + bu) * mask
  const int wr = (w & 1)*64, wc = (w >> 1)*64;
  const size_t growbase = (size_t)b*Nn + i0;
  {
    f32x4 acc[4][4];
#pragma unroll
    for (int m = 0; m < 4; ++m)
#pragma unroll
      for (int n = 0; n < 4; ++n) acc[m][n] = (f32x4){0.f,0.f,0.f,0.f};
#pragma unroll
    for (int kk = 0; kk < 256; kk += 32) {
      bf16x8 bfr[4];
      if (kk < 128) {
#pragma unroll
        for (int n = 0; n < 4; ++n)
          bfr[n] = *(const bf16x8*)(h + (growbase + wr + n*16 + l15)*128 + kk + 8*g);
      } else {
#pragma unroll
        for (int n = 0; n < 4; ++n) {
          int lr = wr + n*16 + l15;
          int kl = (kk - 128) + 8*g;
          bfr[n] = *(const bf16x8*)(aggs + lr*128 + (kl ^ ((lr & 7) << 3)));
        }
      }
      bf16x8 wfr[4];
#pragma unroll
      for (int m = 0; m < 4; ++m) {
        int cblk = (wc >> 4) + m;
        wfr[m] = *(const bf16x8*)(WuF + (size_t)(cblk*8 + (kk >> 5))*512 + lane*8);
      }
#pragma unroll
      for (int m = 0; m < 4; ++m)
#pragma unroll
        for (int n = 0; n < 4; ++n)
          acc[m][n] = __builtin_amdgcn_mfma_f32_16x16x32_bf16(wfr[m], bfr[n], acc[m][n], 0,0,0);
    }
    __syncthreads();  // all h reads (cross-wave cols) + aggs reads drained
#pragma unroll
    for (int m = 0; m < 4; ++m) {
      f32x4 bs = *(const f32x4*)(bu + wc + m*16 + g*4);
#pragma unroll
      for (int n = 0; n < 4; ++n) {
        int lr = wr + n*16 + l15;
        size_t r = growbase + lr;
        float mv = mask[r];
        bf16x4 o;
#pragma unroll
        for (int j = 0; j < 4; ++j)
          o[j] = (bf16)(fmaxf(acc[m][n][j] + bs[j], 0.f) * mv);
        int c0 = wc + m*16 + g*4;
        *(bf16x4*)(h + r*128 + c0) = o;
        if (DO_MSG)
          *(bf16x4*)(htile + lr*128 + (c0 ^ ((lr & 7) << 3))) = o;
      }
    }
  }
  if (!DO_MSG) return;
  __syncthreads();   // htile visible

  // ================= Phase C: msgFout = relu(h_new @ Wm + bm)^T (frag-linear)
  {
    f32x4 acc[4][4];
#pragma unroll
    for (int m = 0; m < 4; ++m)
#pragma unroll
      for (int n = 0; n < 4; ++n) acc[m][n] = (f32x4){0.f,0.f,0.f,0.f};
#pragma unroll
    for (int kk = 0; kk < 128; kk += 32) {
      bf16x8 bfr[4], wfr[4];
#pragma unroll
      for (int n = 0; n < 4; ++n) {
        int lr = wr + n*16 + l15;
        bfr[n] = *(const bf16x8*)(htile + lr*128 + ((kk + 8*g) ^ ((lr & 7) << 3)));
      }
#pragma unroll
      for (int m = 0; m < 4; ++m) {
        int cblk = (wc >> 4) + m;
        wfr[m] = *(const bf16x8*)(WmF + (size_t)(cblk*4 + (kk >> 5))*512 + lane*8);
      }
#pragma unroll
      for (int m = 0; m < 4; ++m)
#pragma unroll
        for (int n = 0; n < 4; ++n)
          acc[m][n] = __builtin_amdgcn_mfma_f32_16x16x32_bf16(bfr[n], wfr[m], acc[m][n], 0,0,0);
    }
#pragma unroll
    for (int m = 0; m < 4; ++m) {
      int c = wc + m*16 + l15;
      int mblk = (wc >> 4) + m;
      float bc = bm[c];
#pragma unroll
      for (int n = 0; n < 4; ++n) {
        int rl = i0 + wr + n*16 + g*4;
        bf16x4 o;
#pragma unroll
        for (int j = 0; j < 4; ++j) o[j] = (bf16)fmaxf(acc[m][n][j] + bc, 0.f);
        size_t off = (size_t)b*65536 + (size_t)((rl>>5)*8 + mblk)*512
                   + (((rl>>3)&3)*16 + l15)*8 + (rl&7);
        *(bf16x4*)(msgFout + off) = o;
      }
    }
  }
}

// -------------------------------------------------- fused pool + readout
__global__ __launch_bounds__(256) void pool_readout(
    const bf16* __restrict__ h, const float* __restrict__ mask,
    const float* __restrict__ W1, const float* __restrict__ b1,
    const float* __restrict__ W2, const float* __restrict__ b2,
    float* __restrict__ out) {
  __shared__ float part[3][128];
  __shared__ float pl[128];
  __shared__ float hid[128];
  int b = blockIdx.x, t = threadIdx.x, g = t >> 6, cp = (t & 63)*2;
  float a0 = 0.f, a1 = 0.f;
  for (int n = g*128; n < g*128+128; ++n) {
    float mv = mask[(size_t)b*Nn + n];
    bf16x2 v = *(const bf16x2*)(h + ((size_t)b*Nn + n)*128 + cp);
    a0 = fmaf((float)v[0], mv, a0);
    a1 = fmaf((float)v[1], mv, a1);
  }
  if (g > 0) { part[g-1][cp] = a0; part[g-1][cp+1] = a1; }
  __syncthreads();
  if (g == 0) {
    pl[cp]   = a0 + part[0][cp]   + part[1][cp]   + part[2][cp];
    pl[cp+1] = a1 + part[0][cp+1] + part[1][cp+1] + part[2][cp+1];
  }
  __syncthreads();
  if (t < 128) {
    float a = b1[t];
#pragma unroll 4
    for (int j = 0; j < 128; ++j) a = fmaf(pl[j], W1[j*128 + t], a);
    hid[t] = fmaxf(a, 0.f);
  }
  __syncthreads();
  if (t < 128) {
    float a = b2[t];
#pragma unroll 4
    for (int j = 0; j < 128; ++j) a = fmaf(hid[j], W2[j*128 + t], a);
    out[(size_t)b*128 + t] = a;
  }
}

// -------------------------------------------------- launch
extern "C" void kernel_launch(void* const* d_in, const int* in_sizes, int n_in,
                              void* d_out, int out_size, void* d_ws, size_t ws_size,
                              hipStream_t stream) {
  const float* jets = (const float*)d_in[0];
  const float* mask = (const float*)d_in[1];
  const float* eW0  = (const float*)d_in[2];
  const float* eb0  = (const float*)d_in[3];
  const float* eW1  = (const float*)d_in[4];
  const float* eb1  = (const float*)d_in[5];
  const float* Wm   = (const float*)d_in[6];
  const float* bm   = (const float*)d_in[7];
  const float* Wu   = (const float*)d_in[8];
  const float* bu   = (const float*)d_in[9];
  const float* rW1  = (const float*)d_in[10];
  const float* rb1  = (const float*)d_in[11];
  const float* rW2  = (const float*)d_in[12];
  const float* rb2  = (const float*)d_in[13];
  float* out = (float*)d_out;

  bf16* h     = (bf16*)d_ws;                    // ROWS*128
  bf16* msgFA = h     + (size_t)ROWS*128;       // ROWS*128 (fragment-linear)
  bf16* msgFB = msgFA + (size_t)ROWS*128;       // ROWS*128 (ping-pong)
  bf16* PF    = msgFB + (size_t)ROWS*128;       // Bb*512*512 (67 MB, frag-linear E)
  bf16* WTe   = PF    + (size_t)Bb*512*512;     // 128*128 (old layout)
  bf16* WmF   = WTe   + 128*128;                // 3*128*128 (frag-linear)
  bf16* WuF   = WmF   + 3*128*128;              // 3*256*128 (frag-linear)
  float* rsum = (float*)(WuF + 3*256*128);      // ROWS (1/l_i)

  prep_all<<<640, 256, 0, stream>>>(eW1, Wm, Wu, WTe, WmF, WuF);
  pmat_kernel<<<Bb*4, 256, 0, stream>>>(jets, mask, PF, rsum);
  embed_msg0<<<ROWS/128, 256, 0, stream>>>(jets, eW0, eb0, WTe, eb1,
                                           WmF, bm, h, msgFA);
  // iter 0: msgFA -> msgFB
  iter_fused<true><<<Bb*4, 256, 0, stream>>>(
      PF, rsum, mask, msgFA, h,
      WuF, bu, WmF + (size_t)1*128*128, bm + 1*128, msgFB);
  // iter 1: msgFB -> msgFA
  iter_fused<true><<<Bb*4, 256, 0, stream>>>(
      PF, rsum, mask, msgFB, h,
      WuF + (size_t)1*256*128, bu + 1*128,
      WmF + (size_t)2*128*128, bm + 2*128, msgFA);
  // iter 2 (no next msg): reads msgFA
  iter_fused<false><<<Bb*4, 256, 0, stream>>>(
      PF, rsum, mask, msgFA, h,
      WuF + (size_t)2*256*128, bu + 2*128, nullptr, nullptr, nullptr);

  pool_readout<<<Bb, 256, 0, stream>>>(h, mask, rW1, rb1, rW2, rb2, out);
}